// Round 15
// baseline (602.923 us; speedup 1.0000x reference)
//
#include <hip/hip_runtime.h>
#include <hip/hip_bf16.h>

#define CDIM 192
#define WSZ 7
#define SSZ 3
#define NHEAD 6
#define HD 32
#define NTOK 49          // tokens per window
#define HW 56
#define TTOK (32*56*56)  // 100352 tokens total

#define QSCALE_LOG2E 0.25507817580918256f   // (1/sqrt(32)) * log2(e)
#define MASK_LOG2E  -144.26950408889634f    // -100 * log2(e)
#define LOG2E        1.4426950408889634f

typedef __attribute__((ext_vector_type(8))) short bf16x8;
typedef __attribute__((ext_vector_type(4))) float f32x4;

// manual RNE f32->bf16 (known good)
__device__ inline ushort f2bf(float v) {
    union { float f; unsigned u; } x; x.f = v;
    unsigned r = x.u + 0x7fff + ((x.u >> 16) & 1);
    return (ushort)(r >> 16);
}
// two f32 -> one packed dword (manual, no asm)
__device__ inline unsigned pk2bf(float lo, float hi) {
    return (unsigned)f2bf(lo) | ((unsigned)f2bf(hi) << 16);
}
// bf16 bits -> f32 (exact)
__device__ inline float bf2f(ushort u) {
    union { unsigned u; float f; } x; x.u = ((unsigned)u) << 16;
    return x.f;
}

__device__ inline float gelu_f(float x) {
    // x * sigmoid(2c1*x*(1+c2*x^2)) == tanh-form GELU, exp2 folded
    float x2 = x * x;
    float t  = x * fmaf(x2, 0.10287358f, 2.3022157f);   // (2c1, 2c1c2) * log2(e)
    float e  = __builtin_amdgcn_exp2f(-t);
    return x * __builtin_amdgcn_rcpf(1.0f + e);
}

// ---------------------------------------------------------------------------
// Weight prep: bf16 N-major transposes. Q-part of WqkvT pre-scaled by
// (1/sqrt(hd))*log2(e) so softmax runs in the exp2 domain.
// ---------------------------------------------------------------------------
__global__ __launch_bounds__(256) void prep_weights_kernel(
    const float* __restrict__ fc1_w, const float* __restrict__ fc2_w,
    const float* __restrict__ qkv_w, const float* __restrict__ proj_w,
    ushort* __restrict__ W1T, ushort* __restrict__ W2T,
    ushort* __restrict__ WqkvT, ushort* __restrict__ PjT) {
    int idx = blockIdx.x * 256 + threadIdx.x;  // grid covers exactly 147456
    {
        int n = idx / 192, k = idx - n * 192;
        W1T[idx] = f2bf(fc1_w[k * 768 + n]);
    }
    {
        int c = idx / 768, k = idx - c * 768;
        W2T[idx] = f2bf(fc2_w[k * 192 + c]);
    }
    if (idx < 576 * 192) {
        int n = idx / 192, k = idx - n * 192;
        float v = qkv_w[k * 576 + n];
        if (n < 192) v *= QSCALE_LOG2E;
        WqkvT[idx] = f2bf(v);
    }
    if (idx < 192 * 192) {
        int n = idx / 192, k = idx - n * 192;
        PjT[idx] = f2bf(proj_w[k * 192 + n]);
    }
}

// ---------------------------------------------------------------------------
// LN1 + window gather: xnw[win][64][192] bf16 (window-major slabs, shifted,
// pad rows 49-63 zero). One block per window; token reads are 768-B
// contiguous per token (4 adjacent lanes); slab writes fully coalesced.
// xnw lives in d_out (scratch until mlp overwrites).
// ---------------------------------------------------------------------------
__global__ __launch_bounds__(256) void ln1w_kernel(
    const float* __restrict__ x,
    const float* __restrict__ g1, const float* __restrict__ b1,
    ushort* __restrict__ xnw)
{
    const int bid = blockIdx.x;
    const int b   = bid >> 6;
    const int w   = bid & 63;
    const int wh  = w >> 3, ww = w & 7;
    const int tid = threadIdx.x;
    const int n   = tid >> 2;
    const int c0  = (tid & 3) * 48;
    ushort* o = xnw + ((size_t)bid * 64 + n) * CDIM + c0;

    if (n < NTOK) {
        int i = n / 7, j = n - i * 7;
        int hs = wh * 7 + i + SSZ; if (hs >= HW) hs -= HW;
        int ws = ww * 7 + j + SSZ; if (ws >= HW) ws -= HW;
        size_t tok = ((size_t)b * HW + hs) * HW + ws;
        const float4* xr = (const float4*)(x + tok * CDIM + c0);
        float4 f[12];
        float s = 0.0f, q = 0.0f;
        #pragma unroll
        for (int j4 = 0; j4 < 12; j4++) {
            float4 v = xr[j4]; f[j4] = v;
            s += v.x + v.y + v.z + v.w;
            q += v.x * v.x + v.y * v.y + v.z * v.z + v.w * v.w;
        }
        s += __shfl_xor(s, 1); s += __shfl_xor(s, 2);
        q += __shfl_xor(q, 1); q += __shfl_xor(q, 2);
        float mean = s * (1.0f / 192.0f);
        float rstd = rsqrtf(q * (1.0f / 192.0f) - mean * mean + 1e-5f);
        const float4* gg = (const float4*)(g1 + c0);
        const float4* bb = (const float4*)(b1 + c0);
        #pragma unroll
        for (int j4 = 0; j4 < 12; j4++) {
            float4 v = f[j4], g = gg[j4], bv = bb[j4];
            unsigned p0 = pk2bf((v.x - mean) * rstd * g.x + bv.x,
                                (v.y - mean) * rstd * g.y + bv.y);
            unsigned p1 = pk2bf((v.z - mean) * rstd * g.z + bv.z,
                                (v.w - mean) * rstd * g.w + bv.w);
            *(uint2*)&o[j4 * 4] = make_uint2(p0, p1);
        }
    } else {
        #pragma unroll
        for (int j4 = 0; j4 < 12; j4++)
            *(uint2*)&o[j4 * 4] = make_uint2(0u, 0u);
    }
}

// ---------------------------------------------------------------------------
// MFMA shifted-window attention: A-fragments from window-major xnw slab
// (line-exact loads, L2-hot). No A LDS, no staging phase -> 50.1 KB LDS
// -> 3 blocks/CU. Head-pair loop, N-split QKV/proj, M-split softmax.
// ---------------------------------------------------------------------------
__global__ __launch_bounds__(256, 3) void attn_mfma_kernel(
    const float*  __restrict__ x,
    const ushort* __restrict__ xnw,
    const ushort* __restrict__ WqkvT, const float* __restrict__ qkv_b,
    const float*  __restrict__ rpb,
    const ushort* __restrict__ PjT, const float* __restrict__ proj_b,
    ushort* __restrict__ x2)
{
    __shared__ ushort Qs[64 * 72];    //  9216 B  q (pre-scaled), [tok][pairdim]
    __shared__ ushort Ks[64 * 72];    //  9216 B  k, [tok][pairdim]
    __shared__ ushort Vs[64 * 72];    //  9216 B  v, [pairdim][tok]
    __shared__ ushort Ps[64 * 72];    //  9216 B  P, [tok][kv] (wave-private rows)
    __shared__ ushort Ho[64 * 72];    //  9216 B  head-pair out, [tok][pairdim]
    __shared__ float  rpbl[169 * 6];  //  4056 B   -> 50136 B, 3 blocks/CU

    const int bid = blockIdx.x;
    const int b   = bid >> 6;
    const int w   = bid & 63;
    const int wh  = w >> 3, ww = w & 7;
    const int tid = threadIdx.x;
    const int l   = tid & 63;
    const int wid = tid >> 6;

    for (int e = tid; e < 169 * 6; e += 256) rpbl[e] = rpb[e] * LOG2E;

    const int lrow = l & 15;
    const int rg   = l >> 4;
    const int kg   = rg * 8;
    const int m0   = wid * 16;
    const int arow = m0 + lrow;

    // slab base for this window; fragment rows are bid*64 + m*16 + lrow
    const ushort* slab = xnw + (size_t)bid * 64 * CDIM;

    // per-lane bias/mask tables: score[i=m0+rg*4+jj][j=nt*16+lrow]
    int   rpi16[4][4];
    float madd[4][4];
    #pragma unroll
    for (int jj = 0; jj < 4; jj++) {
        int i  = m0 + rg * 4 + jj;
        int ih = (i * 9363) >> 16, iw = i - ih * 7;
        int pi = wh * 7 + ih, qi = ww * 7 + iw;
        int ci = (pi < 49 ? 0 : (pi < 53 ? 1 : 2)) * 3 + (qi < 49 ? 0 : (qi < 53 ? 1 : 2));
        #pragma unroll
        for (int nt = 0; nt < 4; nt++) {
            int j  = nt * 16 + lrow;
            int jh = (j * 9363) >> 16, jw = j - jh * 7;
            int pj = wh * 7 + jh, qj = ww * 7 + jw;
            int cj = (pj < 49 ? 0 : (pj < 53 ? 1 : 2)) * 3 + (qj < 49 ? 0 : (qj < 53 ? 1 : 2));
            int rpi = (ih - jh + 6) * 13 + (iw - jw + 6);
            rpi = rpi < 0 ? 0 : (rpi > 168 ? 168 : rpi);
            rpi16[jj][nt] = rpi * 6;
            madd[jj][nt] = (j >= NTOK) ? -1e30f : ((ci != cj) ? MASK_LOG2E : 0.0f);
        }
    }

    f32x4 acc2[3][4];   // proj: [n-tile][m-tile], wave owns cols wid*48..+48
    #pragma unroll
    for (int nt = 0; nt < 3; nt++)
        #pragma unroll
        for (int m = 0; m < 4; m++) acc2[nt][m] = (f32x4){0.f, 0.f, 0.f, 0.f};

    for (int p = 0; p < 3; p++) {
        const int h0 = p * 2;

        // A-fragments straight from the window slab (pad rows are zero)
        bf16x8 a1[4][6];
        #pragma unroll
        for (int m = 0; m < 4; m++)
            #pragma unroll
            for (int ks = 0; ks < 6; ks++)
                a1[m][ks] = *(const bf16x8*)&slab[(m * 16 + lrow) * CDIM + ks * 32 + kg];

        // ---- QKV, N-split: wave handles 3 of 12 tiles, serial B loads ----
        #pragma unroll
        for (int tt = 0; tt < 3; tt++) {
            const int t    = wid * 3 + tt;
            const int kind = t >> 2;          // 0=Q 1=K 2=V (wave-uniform)
            const int sub  = t & 3;
            const int hh   = sub >> 1, half = sub & 1;
            const int dim2 = hh * 32 + half * 16 + lrow;
            const int nglob = kind * 192 + (h0 + hh) * 32 + half * 16;
            const ushort* bp = WqkvT + (size_t)(nglob + lrow) * 192 + kg;
            bf16x8 bfr[6];
            #pragma unroll
            for (int ks = 0; ks < 6; ks++)
                bfr[ks] = *(const bf16x8*)(bp + ks * 32);
            float bias = qkv_b[nglob + lrow];
            if (kind == 0) bias *= QSCALE_LOG2E;   // W already pre-scaled
            #pragma unroll
            for (int m = 0; m < 4; m++) {
                f32x4 a = (f32x4){0.f, 0.f, 0.f, 0.f};
                #pragma unroll
                for (int ks = 0; ks < 6; ks++)
                    a = __builtin_amdgcn_mfma_f32_16x16x32_bf16(a1[m][ks], bfr[ks], a, 0, 0, 0);
                float v0 = a[0] + bias, v1 = a[1] + bias;
                float v2 = a[2] + bias, v3 = a[3] + bias;
                if (kind == 2) {
                    *(uint2*)&Vs[dim2 * 72 + m * 16 + rg * 4] =
                        make_uint2(pk2bf(v0, v1), pk2bf(v2, v3));
                } else {
                    ushort* dst = (kind == 0) ? Qs : Ks;
                    int base = (m * 16 + rg * 4) * 72 + dim2;
                    dst[base +   0] = f2bf(v0);
                    dst[base +  72] = f2bf(v1);
                    dst[base + 144] = f2bf(v2);
                    dst[base + 216] = f2bf(v3);
                }
            }
        }
        __syncthreads();

        // ---- per head: scores + softmax(exp2) + PV (wave-local M-band) ----
        #pragma unroll
        for (int hh = 0; hh < 2; hh++) {
            const int h = h0 + hh;
            bf16x8 aq = *(const bf16x8*)&Qs[arow * 72 + hh * 32 + kg];
            f32x4 s4[4];
            #pragma unroll
            for (int nt = 0; nt < 4; nt++) {
                bf16x8 bk = *(const bf16x8*)&Ks[(nt * 16 + lrow) * 72 + hh * 32 + kg];
                f32x4 a = (f32x4){0.f, 0.f, 0.f, 0.f};
                a = __builtin_amdgcn_mfma_f32_16x16x32_bf16(aq, bk, a, 0, 0, 0);
                #pragma unroll
                for (int jj = 0; jj < 4; jj++)
                    s4[nt][jj] = a[jj] + rpbl[rpi16[jj][nt] + h] + madd[jj][nt];
            }

            #pragma unroll
            for (int jj = 0; jj < 4; jj++) {
                float m = fmaxf(fmaxf(s4[0][jj], s4[1][jj]), fmaxf(s4[2][jj], s4[3][jj]));
                #pragma unroll
                for (int msk = 1; msk < 16; msk <<= 1) m = fmaxf(m, __shfl_xor(m, msk));
                float e0 = __builtin_amdgcn_exp2f(s4[0][jj] - m);
                float e1 = __builtin_amdgcn_exp2f(s4[1][jj] - m);
                float e2 = __builtin_amdgcn_exp2f(s4[2][jj] - m);
                float e3 = __builtin_amdgcn_exp2f(s4[3][jj] - m);
                float r = e0 + e1 + e2 + e3;
                #pragma unroll
                for (int msk = 1; msk < 16; msk <<= 1) r += __shfl_xor(r, msk);
                float inv = 1.0f / r;
                int prow = (m0 + rg * 4 + jj) * 72;
                Ps[prow +  0 + lrow] = f2bf(e0 * inv);
                Ps[prow + 16 + lrow] = f2bf(e1 * inv);
                Ps[prow + 32 + lrow] = f2bf(e2 * inv);
                Ps[prow + 48 + lrow] = f2bf(e3 * inv);
            }

            #pragma unroll
            for (int nt = 0; nt < 2; nt++) {
                f32x4 a = (f32x4){0.f, 0.f, 0.f, 0.f};
                #pragma unroll
                for (int ks = 0; ks < 2; ks++) {
                    bf16x8 pa = *(const bf16x8*)&Ps[arow * 72 + ks * 32 + kg];
                    bf16x8 bv = *(const bf16x8*)&Vs[(hh * 32 + nt * 16 + lrow) * 72 + ks * 32 + kg];
                    a = __builtin_amdgcn_mfma_f32_16x16x32_bf16(pa, bv, a, 0, 0, 0);
                }
                int hcol = hh * 32 + nt * 16 + lrow;
                int hbase = (m0 + rg * 4) * 72 + hcol;
                Ho[hbase +   0] = f2bf(a[0]);
                Ho[hbase +  72] = f2bf(a[1]);
                Ho[hbase + 144] = f2bf(a[2]);
                Ho[hbase + 216] = f2bf(a[3]);
            }
        }
        __syncthreads();

        // ---- proj, N-split: global B loads hoisted ahead of LDS reads ----
        bf16x8 pj[3][2];
        #pragma unroll
        for (int nt = 0; nt < 3; nt++) {
            const ushort* bp = PjT + (size_t)(wid * 48 + nt * 16 + lrow) * 192 + p * 64 + kg;
            pj[nt][0] = *(const bf16x8*)(bp);
            pj[nt][1] = *(const bf16x8*)(bp + 32);
        }
        bf16x8 aH[4][2];
        #pragma unroll
        for (int m = 0; m < 4; m++)
            #pragma unroll
            for (int ks = 0; ks < 2; ks++)
                aH[m][ks] = *(const bf16x8*)&Ho[(m * 16 + lrow) * 72 + ks * 32 + kg];
        #pragma unroll
        for (int nt = 0; nt < 3; nt++)
            #pragma unroll
            for (int m = 0; m < 4; m++) {
                acc2[nt][m] = __builtin_amdgcn_mfma_f32_16x16x32_bf16(aH[m][0], pj[nt][0], acc2[nt][m], 0, 0, 0);
                acc2[nt][m] = __builtin_amdgcn_mfma_f32_16x16x32_bf16(aH[m][1], pj[nt][1], acc2[nt][m], 0, 0, 0);
            }
    }

    // ---- epilogue: x2 = bf16(x + proj_out + proj_b) (N-split cols, 49 rows) ----
    float pb[3];
    #pragma unroll
    for (int nt = 0; nt < 3; nt++) pb[nt] = proj_b[wid * 48 + nt * 16 + lrow];
    #pragma unroll
    for (int m = 0; m < 4; m++) {
        #pragma unroll
        for (int jj = 0; jj < 4; jj++) {
            int n = m * 16 + rg * 4 + jj;
            if (n < NTOK) {
                int i = (n * 9363) >> 16, j = n - i * 7;
                int hs = wh * 7 + i + SSZ; if (hs >= HW) hs -= HW;
                int ws = ww * 7 + j + SSZ; if (ws >= HW) ws -= HW;
                size_t gb = (((size_t)b * HW + hs) * HW + ws) * CDIM;
                #pragma unroll
                for (int nt = 0; nt < 3; nt++) {
                    int c = wid * 48 + nt * 16 + lrow;
                    x2[gb + c] = f2bf(x[gb + c] + pb[nt] + acc2[nt][m][jj]);
                }
            }
        }
    }
}

// ---------------------------------------------------------------------------
// MFMA MLP v5 (unchanged): bf16 x2 input, chunk 384, N-split waves,
// in-kernel LN2, 2-deep B prefetch. 75.8 KB LDS.
// ---------------------------------------------------------------------------
__global__ __launch_bounds__(256, 2) void mlp_mfma_kernel(
    const ushort* __restrict__ x2,
    const float*  __restrict__ g2, const float* __restrict__ b2,
    const ushort* __restrict__ W1T, const float* __restrict__ fc1_b,
    const ushort* __restrict__ W2T, const float* __restrict__ fc2_b,
    float* __restrict__ out)
{
    __shared__ ushort A[64 * 200];    // 25600 B
    __shared__ ushort Hs[64 * 392];   // 50176 B -> 75776 B total

    const int tid = threadIdx.x;
    const int l   = tid & 63;
    const int wid = tid >> 6;
    const size_t tok0 = (size_t)blockIdx.x * 64;

    // ---- stage LN2(x2) tile as bf16, stats in-kernel (bf16 input) ----
    {
        int n  = tid >> 2;
        int c0 = (tid & 3) * 48;
        size_t tok = tok0 + n;
        const bf16x8* xr = (const bf16x8*)(x2 + tok * CDIM + c0);
        float f[48];
        float s = 0.0f, q = 0.0f;
        #pragma unroll
        for (int j8 = 0; j8 < 6; j8++) {
            bf16x8 v = xr[j8];
            #pragma unroll
            for (int e = 0; e < 8; e++) {
                float fv = bf2f((ushort)v[e]);
                f[j8 * 8 + e] = fv;
                s += fv;
                q += fv * fv;
            }
        }
        s += __shfl_xor(s, 1); s += __shfl_xor(s, 2);
        q += __shfl_xor(q, 1); q += __shfl_xor(q, 2);
        float mean = s * (1.0f / 192.0f);
        float rstd = rsqrtf(q * (1.0f / 192.0f) - mean * mean + 1e-5f);
        const float4* gg = (const float4*)(g2 + c0);
        const float4* bb = (const float4*)(b2 + c0);
        #pragma unroll
        for (int j4 = 0; j4 < 12; j4++) {
            float4 g = gg[j4], b = bb[j4];
            int c = n * 200 + c0 + j4 * 4;
            unsigned p0 = pk2bf((f[j4 * 4 + 0] - mean) * rstd * g.x + b.x,
                                (f[j4 * 4 + 1] - mean) * rstd * g.y + b.y);
            unsigned p1 = pk2bf((f[j4 * 4 + 2] - mean) * rstd * g.z + b.z,
                                (f[j4 * 4 + 3] - mean) * rstd * g.w + b.w);
            *(uint2*)&A[c] = make_uint2(p0, p1);
        }
    }
    __syncthreads();

    const int lrow = l & 15;
    const int rg   = l >> 4;
    const int kg   = rg * 8;

    f32x4 acc2[3][4];
    #pragma unroll
    for (int nt = 0; nt < 3; nt++)
        #pragma unroll
        for (int m = 0; m < 4; m++) acc2[nt][m] = (f32x4){0.f, 0.f, 0.f, 0.f};

    for (int ch = 0; ch < 2; ch++) {
        const int h0 = ch * 384;
        if (ch) __syncthreads();   // prior GEMM2 reads of Hs complete

        // hoisted fc1 biases for this wave's 6 tiles
        float bias1[6];
        #pragma unroll
        for (int nt = 0; nt < 6; nt++)
            bias1[nt] = fc1_b[h0 + wid * 96 + nt * 16 + lrow];

        // first B tile prefetch (issue before LDS a1 reads)
        bf16x8 wb0[6], wb1[6];
        {
            const ushort* bp = W1T + (size_t)(h0 + wid * 96 + lrow) * 192 + kg;
            #pragma unroll
            for (int ks = 0; ks < 6; ks++) wb0[ks] = *(const bf16x8*)(bp + ks * 32);
        }

        bf16x8 a1[4][6];
        #pragma unroll
        for (int m = 0; m < 4; m++)
            #pragma unroll
            for (int ks = 0; ks < 6; ks++)
                a1[m][ks] = *(const bf16x8*)&A[(m * 16 + lrow) * 200 + ks * 32 + kg];

        // ---- GEMM1 with 2-deep pipeline: H[:, wave 96-col slice] ----
        #pragma unroll
        for (int nt = 0; nt < 6; nt++) {
            if (nt < 5) {
                const ushort* bp = W1T + (size_t)(h0 + wid * 96 + (nt + 1) * 16 + lrow) * 192 + kg;
                bf16x8* nxt = (nt & 1) ? wb0 : wb1;
                #pragma unroll
                for (int ks = 0; ks < 6; ks++) nxt[ks] = *(const bf16x8*)(bp + ks * 32);
            }
            const bf16x8* cur = (nt & 1) ? wb1 : wb0;
            const int ncol = wid * 96 + nt * 16;
            #pragma unroll
            for (int m = 0; m < 4; m++) {
                f32x4 a = (f32x4){0.f, 0.f, 0.f, 0.f};
                #pragma unroll
                for (int ks = 0; ks < 6; ks++)
                    a = __builtin_amdgcn_mfma_f32_16x16x32_bf16(a1[m][ks], cur[ks], a, 0, 0, 0);
                #pragma unroll
                for (int jj = 0; jj < 4; jj++)
                    Hs[(m * 16 + rg * 4 + jj) * 392 + ncol + lrow] = f2bf(gelu_f(a[jj] + bias1[nt]));
            }
        }
        __syncthreads();

        // ---- GEMM2 with 2-deep pipeline: acc2 += H_chunk @ W2 slice ----
        bf16x8 c0[12], c1[12];
        {
            #pragma unroll
            for (int nt = 0; nt < 3; nt++) {
                const ushort* bp = W2T + (size_t)(wid * 48 + nt * 16 + lrow) * 768 + h0 + kg;
                #pragma unroll
                for (int ks = 0; ks < 4; ks++) c0[nt * 4 + ks] = *(const bf16x8*)(bp + ks * 32);
            }
        }
        #pragma unroll
        for (int ksb = 0; ksb < 3; ksb++) {
            const int kb = ksb * 128;
            if (ksb < 2) {
                bf16x8* nxt = (ksb & 1) ? c0 : c1;
                #pragma unroll
                for (int nt = 0; nt < 3; nt++) {
                    const ushort* bp = W2T + (size_t)(wid * 48 + nt * 16 + lrow) * 768 + h0 + kb + 128 + kg;
                    #pragma unroll
                    for (int ks = 0; ks < 4; ks++) nxt[nt * 4 + ks] = *(const bf16x8*)(bp + ks * 32);
                }
            }
            const bf16x8* cur = (ksb & 1) ? c1 : c0;
            bf16x8 aH[4][4];
            #pragma unroll
            for (int m = 0; m < 4; m++)
                #pragma unroll
                for (int ks = 0; ks < 4; ks++)
                    aH[m][ks] = *(const bf16x8*)&Hs[(m * 16 + lrow) * 392 + kb + ks * 32 + kg];
            #pragma unroll
            for (int nt = 0; nt < 3; nt++)
                #pragma unroll
                for (int m = 0; m < 4; m++)
                    #pragma unroll
                    for (int ks = 0; ks < 4; ks++)
                        acc2[nt][m] = __builtin_amdgcn_mfma_f32_16x16x32_bf16(
                            aH[m][ks], cur[nt * 4 + ks], acc2[nt][m], 0, 0, 0);
        }
    }

    // ---- epilogue: out = x2 + acc2 + fc2_b (bf16 residual read) ----
    #pragma unroll
    for (int nt = 0; nt < 3; nt++) {
        int c = wid * 48 + nt * 16 + lrow;
        float fb = fc2_b[c];
        #pragma unroll
        for (int m = 0; m < 4; m++) {
            #pragma unroll
            for (int jj = 0; jj < 4; jj++) {
                size_t tok = tok0 + m * 16 + rg * 4 + jj;
                out[tok * CDIM + c] = bf2f(x2[tok * CDIM + c]) + acc2[nt][m][jj] + fb;
            }
        }
    }
}

// ---------------------------------------------------------------------------
extern "C" void kernel_launch(void* const* d_in, const int* in_sizes, int n_in,
                              void* d_out, int out_size, void* d_ws, size_t ws_size,
                              hipStream_t stream) {
    const float* x      = (const float*)d_in[0];
    const float* g1     = (const float*)d_in[1];
    const float* b1     = (const float*)d_in[2];
    const float* qkv_w  = (const float*)d_in[3];
    const float* qkv_b  = (const float*)d_in[4];
    const float* rpb    = (const float*)d_in[5];
    const float* proj_w = (const float*)d_in[6];
    const float* proj_b = (const float*)d_in[7];
    const float* g2     = (const float*)d_in[8];
    const float* b2     = (const float*)d_in[9];
    const float* fc1_w  = (const float*)d_in[10];
    const float* fc1_b  = (const float*)d_in[11];
    const float* fc2_w  = (const float*)d_in[12];
    const float* fc2_b  = (const float*)d_in[13];
    float* out = (float*)d_out;

    char* ws = (char*)d_ws;
    ushort* x2     = (ushort*)ws;                     // 38535168 B (bf16)
    ushort* W1T    = (ushort*)(ws + 38535168);        //   294912 B
    ushort* W2T    = (ushort*)(ws + 38830080);        //   294912 B
    ushort* WqkvT  = (ushort*)(ws + 39124992);        //   221184 B
    ushort* PjT    = (ushort*)(ws + 39346176);        //    73728 B

    // xnw (window-major LN1'd slabs, 50.3 MB bf16) lives in d_out:
    // dead before mlp writes the final output.
    ushort* xnw = (ushort*)d_out;

    prep_weights_kernel<<<576, 256, 0, stream>>>(fc1_w, fc2_w, qkv_w, proj_w,
                                                 W1T, W2T, WqkvT, PjT);
    ln1w_kernel<<<32 * 64, 256, 0, stream>>>(x, g1, b1, xnw);
    attn_mfma_kernel<<<32 * 64, 256, 0, stream>>>(x, xnw,
                                                  WqkvT, qkv_b, rpb,
                                                  PjT, proj_b, x2);
    mlp_mfma_kernel<<<TTOK / 64, 256, 0, stream>>>(x2, g2, b2,
                                                   W1T, fc1_b, W2T, fc2_b, out);
}

// Round 16
// 351.373 us; speedup vs baseline: 1.7159x; 1.7159x over previous
//
#include <hip/hip_runtime.h>
#include <hip/hip_bf16.h>

#define CDIM 192
#define WSZ 7
#define SSZ 3
#define NHEAD 6
#define HD 32
#define NTOK 49          // tokens per window
#define HW 56
#define TTOK (32*56*56)  // 100352 tokens total

#define QSCALE_LOG2E 0.25507817580918256f   // (1/sqrt(32)) * log2(e)
#define MASK_LOG2E  -144.26950408889634f    // -100 * log2(e)
#define LOG2E        1.4426950408889634f

typedef __attribute__((ext_vector_type(8))) short bf16x8;
typedef __attribute__((ext_vector_type(4))) float f32x4;

// manual RNE f32->bf16 (known good)
__device__ inline ushort f2bf(float v) {
    union { float f; unsigned u; } x; x.f = v;
    unsigned r = x.u + 0x7fff + ((x.u >> 16) & 1);
    return (ushort)(r >> 16);
}
// two f32 -> one packed dword (manual, no asm)
__device__ inline unsigned pk2bf(float lo, float hi) {
    return (unsigned)f2bf(lo) | ((unsigned)f2bf(hi) << 16);
}
// bf16 bits -> f32 (exact)
__device__ inline float bf2f(ushort u) {
    union { unsigned u; float f; } x; x.u = ((unsigned)u) << 16;
    return x.f;
}

__device__ inline float gelu_f(float x) {
    // x * sigmoid(2c1*x*(1+c2*x^2)) == tanh-form GELU, exp2 folded
    float x2 = x * x;
    float t  = x * fmaf(x2, 0.10287358f, 2.3022157f);   // (2c1, 2c1c2) * log2(e)
    float e  = __builtin_amdgcn_exp2f(-t);
    return x * __builtin_amdgcn_rcpf(1.0f + e);
}

// ---------------------------------------------------------------------------
// Weight prep: bf16 N-major transposes. Q-part of WqkvT pre-scaled by
// (1/sqrt(hd))*log2(e) so softmax runs in the exp2 domain.
// ---------------------------------------------------------------------------
__global__ __launch_bounds__(256) void prep_weights_kernel(
    const float* __restrict__ fc1_w, const float* __restrict__ fc2_w,
    const float* __restrict__ qkv_w, const float* __restrict__ proj_w,
    ushort* __restrict__ W1T, ushort* __restrict__ W2T,
    ushort* __restrict__ WqkvT, ushort* __restrict__ PjT) {
    int idx = blockIdx.x * 256 + threadIdx.x;  // grid covers exactly 147456
    {
        int n = idx / 192, k = idx - n * 192;
        W1T[idx] = f2bf(fc1_w[k * 768 + n]);
    }
    {
        int c = idx / 768, k = idx - c * 768;
        W2T[idx] = f2bf(fc2_w[k * 192 + c]);
    }
    if (idx < 576 * 192) {
        int n = idx / 192, k = idx - n * 192;
        float v = qkv_w[k * 576 + n];
        if (n < 192) v *= QSCALE_LOG2E;
        WqkvT[idx] = f2bf(v);
    }
    if (idx < 192 * 192) {
        int n = idx / 192, k = idx - n * 192;
        PjT[idx] = f2bf(proj_w[k * 192 + n]);
    }
}

// ---------------------------------------------------------------------------
// LN1 + window gather: xnw[win][64][192] bf16 (window-major slabs, shifted,
// pad rows 49-63 zero). One block per window. Lives in d_out (scratch).
// ---------------------------------------------------------------------------
__global__ __launch_bounds__(256) void ln1w_kernel(
    const float* __restrict__ x,
    const float* __restrict__ g1, const float* __restrict__ b1,
    ushort* __restrict__ xnw)
{
    const int bid = blockIdx.x;
    const int b   = bid >> 6;
    const int w   = bid & 63;
    const int wh  = w >> 3, ww = w & 7;
    const int tid = threadIdx.x;
    const int n   = tid >> 2;
    const int c0  = (tid & 3) * 48;
    ushort* o = xnw + ((size_t)bid * 64 + n) * CDIM + c0;

    if (n < NTOK) {
        int i = n / 7, j = n - i * 7;
        int hs = wh * 7 + i + SSZ; if (hs >= HW) hs -= HW;
        int ws = ww * 7 + j + SSZ; if (ws >= HW) ws -= HW;
        size_t tok = ((size_t)b * HW + hs) * HW + ws;
        const float4* xr = (const float4*)(x + tok * CDIM + c0);
        float4 f[12];
        float s = 0.0f, q = 0.0f;
        #pragma unroll
        for (int j4 = 0; j4 < 12; j4++) {
            float4 v = xr[j4]; f[j4] = v;
            s += v.x + v.y + v.z + v.w;
            q += v.x * v.x + v.y * v.y + v.z * v.z + v.w * v.w;
        }
        s += __shfl_xor(s, 1); s += __shfl_xor(s, 2);
        q += __shfl_xor(q, 1); q += __shfl_xor(q, 2);
        float mean = s * (1.0f / 192.0f);
        float rstd = rsqrtf(q * (1.0f / 192.0f) - mean * mean + 1e-5f);
        const float4* gg = (const float4*)(g1 + c0);
        const float4* bb = (const float4*)(b1 + c0);
        #pragma unroll
        for (int j4 = 0; j4 < 12; j4++) {
            float4 v = f[j4], g = gg[j4], bv = bb[j4];
            unsigned p0 = pk2bf((v.x - mean) * rstd * g.x + bv.x,
                                (v.y - mean) * rstd * g.y + bv.y);
            unsigned p1 = pk2bf((v.z - mean) * rstd * g.z + bv.z,
                                (v.w - mean) * rstd * g.w + bv.w);
            *(uint2*)&o[j4 * 4] = make_uint2(p0, p1);
        }
    } else {
        #pragma unroll
        for (int j4 = 0; j4 < 12; j4++)
            *(uint2*)&o[j4 * 4] = make_uint2(0u, 0u);
    }
}

// ---------------------------------------------------------------------------
// MFMA shifted-window attention: A-fragments from window-major xnw slab
// (line-exact loads, L2-hot). No A LDS -> 50.1 KB -> LDS-limited 3 blocks/CU.
// launch_bounds(256,2): let the allocator use ~128 VGPR (no forced cap).
// ---------------------------------------------------------------------------
__global__ __launch_bounds__(256, 2) void attn_mfma_kernel(
    const float*  __restrict__ x,
    const ushort* __restrict__ xnw,
    const ushort* __restrict__ WqkvT, const float* __restrict__ qkv_b,
    const float*  __restrict__ rpb,
    const ushort* __restrict__ PjT, const float* __restrict__ proj_b,
    ushort* __restrict__ x2)
{
    __shared__ ushort Qs[64 * 72];    //  9216 B  q (pre-scaled), [tok][pairdim]
    __shared__ ushort Ks[64 * 72];    //  9216 B  k, [tok][pairdim]
    __shared__ ushort Vs[64 * 72];    //  9216 B  v, [pairdim][tok]
    __shared__ ushort Ps[64 * 72];    //  9216 B  P, [tok][kv] (wave-private rows)
    __shared__ ushort Ho[64 * 72];    //  9216 B  head-pair out, [tok][pairdim]
    __shared__ float  rpbl[169 * 6];  //  4056 B   -> 50136 B, 3 blocks/CU

    const int bid = blockIdx.x;
    const int b   = bid >> 6;
    const int w   = bid & 63;
    const int wh  = w >> 3, ww = w & 7;
    const int tid = threadIdx.x;
    const int l   = tid & 63;
    const int wid = tid >> 6;

    for (int e = tid; e < 169 * 6; e += 256) rpbl[e] = rpb[e] * LOG2E;

    const int lrow = l & 15;
    const int rg   = l >> 4;
    const int kg   = rg * 8;
    const int m0   = wid * 16;
    const int arow = m0 + lrow;

    // slab base for this window; fragment rows are bid*64 + m*16 + lrow
    const ushort* slab = xnw + (size_t)bid * 64 * CDIM;

    // per-lane bias/mask tables: score[i=m0+rg*4+jj][j=nt*16+lrow]
    int   rpi16[4][4];
    float madd[4][4];
    #pragma unroll
    for (int jj = 0; jj < 4; jj++) {
        int i  = m0 + rg * 4 + jj;
        int ih = (i * 9363) >> 16, iw = i - ih * 7;
        int pi = wh * 7 + ih, qi = ww * 7 + iw;
        int ci = (pi < 49 ? 0 : (pi < 53 ? 1 : 2)) * 3 + (qi < 49 ? 0 : (qi < 53 ? 1 : 2));
        #pragma unroll
        for (int nt = 0; nt < 4; nt++) {
            int j  = nt * 16 + lrow;
            int jh = (j * 9363) >> 16, jw = j - jh * 7;
            int pj = wh * 7 + jh, qj = ww * 7 + jw;
            int cj = (pj < 49 ? 0 : (pj < 53 ? 1 : 2)) * 3 + (qj < 49 ? 0 : (qj < 53 ? 1 : 2));
            int rpi = (ih - jh + 6) * 13 + (iw - jw + 6);
            rpi = rpi < 0 ? 0 : (rpi > 168 ? 168 : rpi);
            rpi16[jj][nt] = rpi * 6;
            madd[jj][nt] = (j >= NTOK) ? -1e30f : ((ci != cj) ? MASK_LOG2E : 0.0f);
        }
    }

    f32x4 acc2[3][4];   // proj: [n-tile][m-tile], wave owns cols wid*48..+48
    #pragma unroll
    for (int nt = 0; nt < 3; nt++)
        #pragma unroll
        for (int m = 0; m < 4; m++) acc2[nt][m] = (f32x4){0.f, 0.f, 0.f, 0.f};

    for (int p = 0; p < 3; p++) {
        const int h0 = p * 2;

        // A-fragments straight from the window slab (pad rows are zero)
        bf16x8 a1[4][6];
        #pragma unroll
        for (int m = 0; m < 4; m++)
            #pragma unroll
            for (int ks = 0; ks < 6; ks++)
                a1[m][ks] = *(const bf16x8*)&slab[(m * 16 + lrow) * CDIM + ks * 32 + kg];

        // ---- QKV, N-split: wave handles 3 of 12 tiles, serial B loads ----
        #pragma unroll
        for (int tt = 0; tt < 3; tt++) {
            const int t    = wid * 3 + tt;
            const int kind = t >> 2;          // 0=Q 1=K 2=V (wave-uniform)
            const int sub  = t & 3;
            const int hh   = sub >> 1, half = sub & 1;
            const int dim2 = hh * 32 + half * 16 + lrow;
            const int nglob = kind * 192 + (h0 + hh) * 32 + half * 16;
            const ushort* bp = WqkvT + (size_t)(nglob + lrow) * 192 + kg;
            bf16x8 bfr[6];
            #pragma unroll
            for (int ks = 0; ks < 6; ks++)
                bfr[ks] = *(const bf16x8*)(bp + ks * 32);
            float bias = qkv_b[nglob + lrow];
            if (kind == 0) bias *= QSCALE_LOG2E;   // W already pre-scaled
            #pragma unroll
            for (int m = 0; m < 4; m++) {
                f32x4 a = (f32x4){0.f, 0.f, 0.f, 0.f};
                #pragma unroll
                for (int ks = 0; ks < 6; ks++)
                    a = __builtin_amdgcn_mfma_f32_16x16x32_bf16(a1[m][ks], bfr[ks], a, 0, 0, 0);
                float v0 = a[0] + bias, v1 = a[1] + bias;
                float v2 = a[2] + bias, v3 = a[3] + bias;
                if (kind == 2) {
                    *(uint2*)&Vs[dim2 * 72 + m * 16 + rg * 4] =
                        make_uint2(pk2bf(v0, v1), pk2bf(v2, v3));
                } else {
                    ushort* dst = (kind == 0) ? Qs : Ks;
                    int base = (m * 16 + rg * 4) * 72 + dim2;
                    dst[base +   0] = f2bf(v0);
                    dst[base +  72] = f2bf(v1);
                    dst[base + 144] = f2bf(v2);
                    dst[base + 216] = f2bf(v3);
                }
            }
        }
        __syncthreads();

        // ---- per head: scores + softmax(exp2) + PV (wave-local M-band) ----
        #pragma unroll
        for (int hh = 0; hh < 2; hh++) {
            const int h = h0 + hh;
            bf16x8 aq = *(const bf16x8*)&Qs[arow * 72 + hh * 32 + kg];
            f32x4 s4[4];
            #pragma unroll
            for (int nt = 0; nt < 4; nt++) {
                bf16x8 bk = *(const bf16x8*)&Ks[(nt * 16 + lrow) * 72 + hh * 32 + kg];
                f32x4 a = (f32x4){0.f, 0.f, 0.f, 0.f};
                a = __builtin_amdgcn_mfma_f32_16x16x32_bf16(aq, bk, a, 0, 0, 0);
                #pragma unroll
                for (int jj = 0; jj < 4; jj++)
                    s4[nt][jj] = a[jj] + rpbl[rpi16[jj][nt] + h] + madd[jj][nt];
            }

            #pragma unroll
            for (int jj = 0; jj < 4; jj++) {
                float m = fmaxf(fmaxf(s4[0][jj], s4[1][jj]), fmaxf(s4[2][jj], s4[3][jj]));
                #pragma unroll
                for (int msk = 1; msk < 16; msk <<= 1) m = fmaxf(m, __shfl_xor(m, msk));
                float e0 = __builtin_amdgcn_exp2f(s4[0][jj] - m);
                float e1 = __builtin_amdgcn_exp2f(s4[1][jj] - m);
                float e2 = __builtin_amdgcn_exp2f(s4[2][jj] - m);
                float e3 = __builtin_amdgcn_exp2f(s4[3][jj] - m);
                float r = e0 + e1 + e2 + e3;
                #pragma unroll
                for (int msk = 1; msk < 16; msk <<= 1) r += __shfl_xor(r, msk);
                float inv = 1.0f / r;
                int prow = (m0 + rg * 4 + jj) * 72;
                Ps[prow +  0 + lrow] = f2bf(e0 * inv);
                Ps[prow + 16 + lrow] = f2bf(e1 * inv);
                Ps[prow + 32 + lrow] = f2bf(e2 * inv);
                Ps[prow + 48 + lrow] = f2bf(e3 * inv);
            }

            #pragma unroll
            for (int nt = 0; nt < 2; nt++) {
                f32x4 a = (f32x4){0.f, 0.f, 0.f, 0.f};
                #pragma unroll
                for (int ks = 0; ks < 2; ks++) {
                    bf16x8 pa = *(const bf16x8*)&Ps[arow * 72 + ks * 32 + kg];
                    bf16x8 bv = *(const bf16x8*)&Vs[(hh * 32 + nt * 16 + lrow) * 72 + ks * 32 + kg];
                    a = __builtin_amdgcn_mfma_f32_16x16x32_bf16(pa, bv, a, 0, 0, 0);
                }
                int hcol = hh * 32 + nt * 16 + lrow;
                int hbase = (m0 + rg * 4) * 72 + hcol;
                Ho[hbase +   0] = f2bf(a[0]);
                Ho[hbase +  72] = f2bf(a[1]);
                Ho[hbase + 144] = f2bf(a[2]);
                Ho[hbase + 216] = f2bf(a[3]);
            }
        }
        __syncthreads();

        // ---- proj, N-split: global B loads hoisted ahead of LDS reads ----
        bf16x8 pj[3][2];
        #pragma unroll
        for (int nt = 0; nt < 3; nt++) {
            const ushort* bp = PjT + (size_t)(wid * 48 + nt * 16 + lrow) * 192 + p * 64 + kg;
            pj[nt][0] = *(const bf16x8*)(bp);
            pj[nt][1] = *(const bf16x8*)(bp + 32);
        }
        bf16x8 aH[4][2];
        #pragma unroll
        for (int m = 0; m < 4; m++)
            #pragma unroll
            for (int ks = 0; ks < 2; ks++)
                aH[m][ks] = *(const bf16x8*)&Ho[(m * 16 + lrow) * 72 + ks * 32 + kg];
        #pragma unroll
        for (int nt = 0; nt < 3; nt++)
            #pragma unroll
            for (int m = 0; m < 4; m++) {
                acc2[nt][m] = __builtin_amdgcn_mfma_f32_16x16x32_bf16(aH[m][0], pj[nt][0], acc2[nt][m], 0, 0, 0);
                acc2[nt][m] = __builtin_amdgcn_mfma_f32_16x16x32_bf16(aH[m][1], pj[nt][1], acc2[nt][m], 0, 0, 0);
            }
    }

    // ---- epilogue: x2 = bf16(x + proj_out + proj_b) (N-split cols, 49 rows) ----
    float pb[3];
    #pragma unroll
    for (int nt = 0; nt < 3; nt++) pb[nt] = proj_b[wid * 48 + nt * 16 + lrow];
    #pragma unroll
    for (int m = 0; m < 4; m++) {
        #pragma unroll
        for (int jj = 0; jj < 4; jj++) {
            int n = m * 16 + rg * 4 + jj;
            if (n < NTOK) {
                int i = (n * 9363) >> 16, j = n - i * 7;
                int hs = wh * 7 + i + SSZ; if (hs >= HW) hs -= HW;
                int ws = ww * 7 + j + SSZ; if (ws >= HW) ws -= HW;
                size_t gb = (((size_t)b * HW + hs) * HW + ws) * CDIM;
                #pragma unroll
                for (int nt = 0; nt < 3; nt++) {
                    int c = wid * 48 + nt * 16 + lrow;
                    x2[gb + c] = f2bf(x[gb + c] + pb[nt] + acc2[nt][m][jj]);
                }
            }
        }
    }
}

// ---------------------------------------------------------------------------
// MFMA MLP v5 (unchanged): bf16 x2 input, chunk 384, N-split waves,
// in-kernel LN2, 2-deep B prefetch. 75.8 KB LDS.
// ---------------------------------------------------------------------------
__global__ __launch_bounds__(256, 2) void mlp_mfma_kernel(
    const ushort* __restrict__ x2,
    const float*  __restrict__ g2, const float* __restrict__ b2,
    const ushort* __restrict__ W1T, const float* __restrict__ fc1_b,
    const ushort* __restrict__ W2T, const float* __restrict__ fc2_b,
    float* __restrict__ out)
{
    __shared__ ushort A[64 * 200];    // 25600 B
    __shared__ ushort Hs[64 * 392];   // 50176 B -> 75776 B total

    const int tid = threadIdx.x;
    const int l   = tid & 63;
    const int wid = tid >> 6;
    const size_t tok0 = (size_t)blockIdx.x * 64;

    // ---- stage LN2(x2) tile as bf16, stats in-kernel (bf16 input) ----
    {
        int n  = tid >> 2;
        int c0 = (tid & 3) * 48;
        size_t tok = tok0 + n;
        const bf16x8* xr = (const bf16x8*)(x2 + tok * CDIM + c0);
        float f[48];
        float s = 0.0f, q = 0.0f;
        #pragma unroll
        for (int j8 = 0; j8 < 6; j8++) {
            bf16x8 v = xr[j8];
            #pragma unroll
            for (int e = 0; e < 8; e++) {
                float fv = bf2f((ushort)v[e]);
                f[j8 * 8 + e] = fv;
                s += fv;
                q += fv * fv;
            }
        }
        s += __shfl_xor(s, 1); s += __shfl_xor(s, 2);
        q += __shfl_xor(q, 1); q += __shfl_xor(q, 2);
        float mean = s * (1.0f / 192.0f);
        float rstd = rsqrtf(q * (1.0f / 192.0f) - mean * mean + 1e-5f);
        const float4* gg = (const float4*)(g2 + c0);
        const float4* bb = (const float4*)(b2 + c0);
        #pragma unroll
        for (int j4 = 0; j4 < 12; j4++) {
            float4 g = gg[j4], b = bb[j4];
            int c = n * 200 + c0 + j4 * 4;
            unsigned p0 = pk2bf((f[j4 * 4 + 0] - mean) * rstd * g.x + b.x,
                                (f[j4 * 4 + 1] - mean) * rstd * g.y + b.y);
            unsigned p1 = pk2bf((f[j4 * 4 + 2] - mean) * rstd * g.z + b.z,
                                (f[j4 * 4 + 3] - mean) * rstd * g.w + b.w);
            *(uint2*)&A[c] = make_uint2(p0, p1);
        }
    }
    __syncthreads();

    const int lrow = l & 15;
    const int rg   = l >> 4;
    const int kg   = rg * 8;

    f32x4 acc2[3][4];
    #pragma unroll
    for (int nt = 0; nt < 3; nt++)
        #pragma unroll
        for (int m = 0; m < 4; m++) acc2[nt][m] = (f32x4){0.f, 0.f, 0.f, 0.f};

    for (int ch = 0; ch < 2; ch++) {
        const int h0 = ch * 384;
        if (ch) __syncthreads();   // prior GEMM2 reads of Hs complete

        // hoisted fc1 biases for this wave's 6 tiles
        float bias1[6];
        #pragma unroll
        for (int nt = 0; nt < 6; nt++)
            bias1[nt] = fc1_b[h0 + wid * 96 + nt * 16 + lrow];

        // first B tile prefetch (issue before LDS a1 reads)
        bf16x8 wb0[6], wb1[6];
        {
            const ushort* bp = W1T + (size_t)(h0 + wid * 96 + lrow) * 192 + kg;
            #pragma unroll
            for (int ks = 0; ks < 6; ks++) wb0[ks] = *(const bf16x8*)(bp + ks * 32);
        }

        bf16x8 a1[4][6];
        #pragma unroll
        for (int m = 0; m < 4; m++)
            #pragma unroll
            for (int ks = 0; ks < 6; ks++)
                a1[m][ks] = *(const bf16x8*)&A[(m * 16 + lrow) * 200 + ks * 32 + kg];

        // ---- GEMM1 with 2-deep pipeline: H[:, wave 96-col slice] ----
        #pragma unroll
        for (int nt = 0; nt < 6; nt++) {
            if (nt < 5) {
                const ushort* bp = W1T + (size_t)(h0 + wid * 96 + (nt + 1) * 16 + lrow) * 192 + kg;
                bf16x8* nxt = (nt & 1) ? wb0 : wb1;
                #pragma unroll
                for (int ks = 0; ks < 6; ks++) nxt[ks] = *(const bf16x8*)(bp + ks * 32);
            }
            const bf16x8* cur = (nt & 1) ? wb1 : wb0;
            const int ncol = wid * 96 + nt * 16;
            #pragma unroll
            for (int m = 0; m < 4; m++) {
                f32x4 a = (f32x4){0.f, 0.f, 0.f, 0.f};
                #pragma unroll
                for (int ks = 0; ks < 6; ks++)
                    a = __builtin_amdgcn_mfma_f32_16x16x32_bf16(a1[m][ks], cur[ks], a, 0, 0, 0);
                #pragma unroll
                for (int jj = 0; jj < 4; jj++)
                    Hs[(m * 16 + rg * 4 + jj) * 392 + ncol + lrow] = f2bf(gelu_f(a[jj] + bias1[nt]));
            }
        }
        __syncthreads();

        // ---- GEMM2 with 2-deep pipeline: acc2 += H_chunk @ W2 slice ----
        bf16x8 c0[12], c1[12];
        {
            #pragma unroll
            for (int nt = 0; nt < 3; nt++) {
                const ushort* bp = W2T + (size_t)(wid * 48 + nt * 16 + lrow) * 768 + h0 + kg;
                #pragma unroll
                for (int ks = 0; ks < 4; ks++) c0[nt * 4 + ks] = *(const bf16x8*)(bp + ks * 32);
            }
        }
        #pragma unroll
        for (int ksb = 0; ksb < 3; ksb++) {
            const int kb = ksb * 128;
            if (ksb < 2) {
                bf16x8* nxt = (ksb & 1) ? c0 : c1;
                #pragma unroll
                for (int nt = 0; nt < 3; nt++) {
                    const ushort* bp = W2T + (size_t)(wid * 48 + nt * 16 + lrow) * 768 + h0 + kb + 128 + kg;
                    #pragma unroll
                    for (int ks = 0; ks < 4; ks++) nxt[nt * 4 + ks] = *(const bf16x8*)(bp + ks * 32);
                }
            }
            const bf16x8* cur = (ksb & 1) ? c1 : c0;
            bf16x8 aH[4][4];
            #pragma unroll
            for (int m = 0; m < 4; m++)
                #pragma unroll
                for (int ks = 0; ks < 4; ks++)
                    aH[m][ks] = *(const bf16x8*)&Hs[(m * 16 + lrow) * 392 + kb + ks * 32 + kg];
            #pragma unroll
            for (int nt = 0; nt < 3; nt++)
                #pragma unroll
                for (int m = 0; m < 4; m++)
                    #pragma unroll
                    for (int ks = 0; ks < 4; ks++)
                        acc2[nt][m] = __builtin_amdgcn_mfma_f32_16x16x32_bf16(
                            aH[m][ks], cur[nt * 4 + ks], acc2[nt][m], 0, 0, 0);
        }
    }

    // ---- epilogue: out = x2 + acc2 + fc2_b (bf16 residual read) ----
    #pragma unroll
    for (int nt = 0; nt < 3; nt++) {
        int c = wid * 48 + nt * 16 + lrow;
        float fb = fc2_b[c];
        #pragma unroll
        for (int m = 0; m < 4; m++) {
            #pragma unroll
            for (int jj = 0; jj < 4; jj++) {
                size_t tok = tok0 + m * 16 + rg * 4 + jj;
                out[tok * CDIM + c] = bf2f(x2[tok * CDIM + c]) + acc2[nt][m][jj] + fb;
            }
        }
    }
}

// ---------------------------------------------------------------------------
extern "C" void kernel_launch(void* const* d_in, const int* in_sizes, int n_in,
                              void* d_out, int out_size, void* d_ws, size_t ws_size,
                              hipStream_t stream) {
    const float* x      = (const float*)d_in[0];
    const float* g1     = (const float*)d_in[1];
    const float* b1     = (const float*)d_in[2];
    const float* qkv_w  = (const float*)d_in[3];
    const float* qkv_b  = (const float*)d_in[4];
    const float* rpb    = (const float*)d_in[5];
    const float* proj_w = (const float*)d_in[6];
    const float* proj_b = (const float*)d_in[7];
    const float* g2     = (const float*)d_in[8];
    const float* b2     = (const float*)d_in[9];
    const float* fc1_w  = (const float*)d_in[10];
    const float* fc1_b  = (const float*)d_in[11];
    const float* fc2_w  = (const float*)d_in[12];
    const float* fc2_b  = (const float*)d_in[13];
    float* out = (float*)d_out;

    char* ws = (char*)d_ws;
    ushort* x2     = (ushort*)ws;                     // 38535168 B (bf16)
    ushort* W1T    = (ushort*)(ws + 38535168);        //   294912 B
    ushort* W2T    = (ushort*)(ws + 38830080);        //   294912 B
    ushort* WqkvT  = (ushort*)(ws + 39124992);        //   221184 B
    ushort* PjT    = (ushort*)(ws + 39346176);        //    73728 B

    // xnw (window-major LN1'd slabs, 50.3 MB bf16) lives in d_out:
    // dead before mlp writes the final output.
    ushort* xnw = (ushort*)d_out;

    prep_weights_kernel<<<576, 256, 0, stream>>>(fc1_w, fc2_w, qkv_w, proj_w,
                                                 W1T, W2T, WqkvT, PjT);
    ln1w_kernel<<<32 * 64, 256, 0, stream>>>(x, g1, b1, xnw);
    attn_mfma_kernel<<<32 * 64, 256, 0, stream>>>(x, xnw,
                                                  WqkvT, qkv_b, rpb,
                                                  PjT, proj_b, x2);
    mlp_mfma_kernel<<<TTOK / 64, 256, 0, stream>>>(x2, g2, b2,
                                                   W1T, fc1_b, W2T, fc2_b, out);
}

// Round 17
// 282.568 us; speedup vs baseline: 2.1337x; 1.2435x over previous
//
#include <hip/hip_runtime.h>
#include <hip/hip_bf16.h>

#define CDIM 192
#define WSZ 7
#define SSZ 3
#define NHEAD 6
#define HD 32
#define NTOK 49          // tokens per window
#define HW 56
#define TTOK (32*56*56)  // 100352 tokens total

#define QSCALE_LOG2E 0.25507817580918256f   // (1/sqrt(32)) * log2(e)
#define MASK_LOG2E  -144.26950408889634f    // -100 * log2(e)
#define LOG2E        1.4426950408889634f

typedef __attribute__((ext_vector_type(8))) short bf16x8;
typedef __attribute__((ext_vector_type(4))) float f32x4;

// manual RNE f32->bf16 (known good)
__device__ inline ushort f2bf(float v) {
    union { float f; unsigned u; } x; x.f = v;
    unsigned r = x.u + 0x7fff + ((x.u >> 16) & 1);
    return (ushort)(r >> 16);
}
// two f32 -> one packed dword (manual, no asm)
__device__ inline unsigned pk2bf(float lo, float hi) {
    return (unsigned)f2bf(lo) | ((unsigned)f2bf(hi) << 16);
}
// bf16 bits -> f32 (exact)
__device__ inline float bf2f(ushort u) {
    union { unsigned u; float f; } x; x.u = ((unsigned)u) << 16;
    return x.f;
}

__device__ inline float gelu_f(float x) {
    // x * sigmoid(2c1*x*(1+c2*x^2)) == tanh-form GELU, exp2 folded
    float x2 = x * x;
    float t  = x * fmaf(x2, 0.10287358f, 2.3022157f);   // (2c1, 2c1c2) * log2(e)
    float e  = __builtin_amdgcn_exp2f(-t);
    return x * __builtin_amdgcn_rcpf(1.0f + e);
}

// ---------------------------------------------------------------------------
// Weight prep: bf16 N-major transposes. Q-part of WqkvT pre-scaled by
// (1/sqrt(hd))*log2(e) so softmax runs in the exp2 domain.
// ---------------------------------------------------------------------------
__global__ __launch_bounds__(256) void prep_weights_kernel(
    const float* __restrict__ fc1_w, const float* __restrict__ fc2_w,
    const float* __restrict__ qkv_w, const float* __restrict__ proj_w,
    ushort* __restrict__ W1T, ushort* __restrict__ W2T,
    ushort* __restrict__ WqkvT, ushort* __restrict__ PjT) {
    int idx = blockIdx.x * 256 + threadIdx.x;  // grid covers exactly 147456
    {
        int n = idx / 192, k = idx - n * 192;
        W1T[idx] = f2bf(fc1_w[k * 768 + n]);
    }
    {
        int c = idx / 768, k = idx - c * 768;
        W2T[idx] = f2bf(fc2_w[k * 192 + c]);
    }
    if (idx < 576 * 192) {
        int n = idx / 192, k = idx - n * 192;
        float v = qkv_w[k * 576 + n];
        if (n < 192) v *= QSCALE_LOG2E;
        WqkvT[idx] = f2bf(v);
    }
    if (idx < 192 * 192) {
        int n = idx / 192, k = idx - n * 192;
        PjT[idx] = f2bf(proj_w[k * 192 + n]);
    }
}

// ---------------------------------------------------------------------------
// MFMA shifted-window attention: head-pair loop, N-split QKV (serial B loads)
// / proj, M-split scores/softmax(exp2)/PV. In-kernel LN1, LDS A staging.
// x2 written as bf16 (halves inter-kernel traffic). LDS 75.7 KB -> 2 blk/CU.
// ---------------------------------------------------------------------------
__global__ __launch_bounds__(256, 2) void attn_mfma_kernel(
    const float*  __restrict__ x,
    const float*  __restrict__ g1, const float* __restrict__ b1,
    const ushort* __restrict__ WqkvT, const float* __restrict__ qkv_b,
    const float*  __restrict__ rpb,
    const ushort* __restrict__ PjT, const float* __restrict__ proj_b,
    ushort* __restrict__ x2)
{
    __shared__ ushort A[64 * 200];    // 25600 B  LN'd tokens (rows 49-63 zero)
    __shared__ ushort Qs[64 * 72];    //  9216 B  q (pre-scaled), [tok][pairdim]
    __shared__ ushort Ks[64 * 72];    //  9216 B  k, [tok][pairdim]
    __shared__ ushort Vs[64 * 72];    //  9216 B  v, [pairdim][tok]
    __shared__ ushort Ps[64 * 72];    //  9216 B  P, [tok][kv] (wave-private rows)
    __shared__ ushort Ho[64 * 72];    //  9216 B  head-pair out, [tok][pairdim]
    __shared__ float  rpbl[169 * 6];  //  4056 B   -> 75736 B total

    const int bid = blockIdx.x;
    const int b   = bid >> 6;
    const int w   = bid & 63;
    const int wh  = w >> 3, ww = w & 7;
    const int tid = threadIdx.x;
    const int l   = tid & 63;
    const int wid = tid >> 6;

    for (int e = tid; e < 169 * 6; e += 256) rpbl[e] = rpb[e] * LOG2E;

    // ---- stage A = LN1(x window, shifted) with in-kernel stats ----
    {
        int n  = tid >> 2;
        int c0 = (tid & 3) * 48;
        if (n < NTOK) {
            int i = n / 7, j = n - i * 7;
            int hs = wh * 7 + i + SSZ; if (hs >= HW) hs -= HW;
            int ws = ww * 7 + j + SSZ; if (ws >= HW) ws -= HW;
            size_t tok = ((size_t)b * HW + hs) * HW + ws;
            const float4* xr = (const float4*)(x + tok * CDIM + c0);
            float4 f[12];
            float s = 0.0f, q = 0.0f;
            #pragma unroll
            for (int j4 = 0; j4 < 12; j4++) {
                float4 v = xr[j4]; f[j4] = v;
                s += v.x + v.y + v.z + v.w;
                q += v.x * v.x + v.y * v.y + v.z * v.z + v.w * v.w;
            }
            s += __shfl_xor(s, 1); s += __shfl_xor(s, 2);
            q += __shfl_xor(q, 1); q += __shfl_xor(q, 2);
            float mean = s * (1.0f / 192.0f);
            float rstd = rsqrtf(q * (1.0f / 192.0f) - mean * mean + 1e-5f);
            const float4* gg = (const float4*)(g1 + c0);
            const float4* bb = (const float4*)(b1 + c0);
            #pragma unroll
            for (int j4 = 0; j4 < 12; j4++) {
                float4 v = f[j4], g = gg[j4], bv = bb[j4];
                int c = n * 200 + c0 + j4 * 4;
                unsigned p0 = pk2bf((v.x - mean) * rstd * g.x + bv.x,
                                    (v.y - mean) * rstd * g.y + bv.y);
                unsigned p1 = pk2bf((v.z - mean) * rstd * g.z + bv.z,
                                    (v.w - mean) * rstd * g.w + bv.w);
                *(uint2*)&A[c] = make_uint2(p0, p1);
            }
        } else {
            #pragma unroll
            for (int j4 = 0; j4 < 12; j4++) {
                int c = n * 200 + c0 + j4 * 4;
                *(uint2*)&A[c] = make_uint2(0u, 0u);
            }
        }
    }
    __syncthreads();

    const int lrow = l & 15;
    const int rg   = l >> 4;
    const int kg   = rg * 8;
    const int m0   = wid * 16;
    const int arow = m0 + lrow;

    // per-lane bias/mask tables: score[i=m0+rg*4+jj][j=nt*16+lrow]
    int   rpi16[4][4];
    float madd[4][4];
    #pragma unroll
    for (int jj = 0; jj < 4; jj++) {
        int i  = m0 + rg * 4 + jj;
        int ih = (i * 9363) >> 16, iw = i - ih * 7;
        int pi = wh * 7 + ih, qi = ww * 7 + iw;
        int ci = (pi < 49 ? 0 : (pi < 53 ? 1 : 2)) * 3 + (qi < 49 ? 0 : (qi < 53 ? 1 : 2));
        #pragma unroll
        for (int nt = 0; nt < 4; nt++) {
            int j  = nt * 16 + lrow;
            int jh = (j * 9363) >> 16, jw = j - jh * 7;
            int pj = wh * 7 + jh, qj = ww * 7 + jw;
            int cj = (pj < 49 ? 0 : (pj < 53 ? 1 : 2)) * 3 + (qj < 49 ? 0 : (qj < 53 ? 1 : 2));
            int rpi = (ih - jh + 6) * 13 + (iw - jw + 6);
            rpi = rpi < 0 ? 0 : (rpi > 168 ? 168 : rpi);
            rpi16[jj][nt] = rpi * 6;
            madd[jj][nt] = (j >= NTOK) ? -1e30f : ((ci != cj) ? MASK_LOG2E : 0.0f);
        }
    }

    f32x4 acc2[3][4];   // proj: [n-tile][m-tile], wave owns cols wid*48..+48
    #pragma unroll
    for (int nt = 0; nt < 3; nt++)
        #pragma unroll
        for (int m = 0; m < 4; m++) acc2[nt][m] = (f32x4){0.f, 0.f, 0.f, 0.f};

    for (int p = 0; p < 3; p++) {
        const int h0 = p * 2;

        bf16x8 a1[4][6];
        #pragma unroll
        for (int m = 0; m < 4; m++)
            #pragma unroll
            for (int ks = 0; ks < 6; ks++)
                a1[m][ks] = *(const bf16x8*)&A[(m * 16 + lrow) * 200 + ks * 32 + kg];

        // ---- QKV, N-split: wave handles 3 of 12 tiles, serial B loads ----
        #pragma unroll
        for (int tt = 0; tt < 3; tt++) {
            const int t    = wid * 3 + tt;
            const int kind = t >> 2;          // 0=Q 1=K 2=V (wave-uniform)
            const int sub  = t & 3;
            const int hh   = sub >> 1, half = sub & 1;
            const int dim2 = hh * 32 + half * 16 + lrow;
            const int nglob = kind * 192 + (h0 + hh) * 32 + half * 16;
            const ushort* bp = WqkvT + (size_t)(nglob + lrow) * 192 + kg;
            bf16x8 bfr[6];
            #pragma unroll
            for (int ks = 0; ks < 6; ks++)
                bfr[ks] = *(const bf16x8*)(bp + ks * 32);
            float bias = qkv_b[nglob + lrow];
            if (kind == 0) bias *= QSCALE_LOG2E;   // W already pre-scaled
            #pragma unroll
            for (int m = 0; m < 4; m++) {
                f32x4 a = (f32x4){0.f, 0.f, 0.f, 0.f};
                #pragma unroll
                for (int ks = 0; ks < 6; ks++)
                    a = __builtin_amdgcn_mfma_f32_16x16x32_bf16(a1[m][ks], bfr[ks], a, 0, 0, 0);
                float v0 = a[0] + bias, v1 = a[1] + bias;
                float v2 = a[2] + bias, v3 = a[3] + bias;
                if (kind == 2) {
                    // 4 consecutive tokens in one row: packed 8B store
                    *(uint2*)&Vs[dim2 * 72 + m * 16 + rg * 4] =
                        make_uint2(pk2bf(v0, v1), pk2bf(v2, v3));
                } else {
                    ushort* dst = (kind == 0) ? Qs : Ks;
                    int base = (m * 16 + rg * 4) * 72 + dim2;
                    dst[base +   0] = f2bf(v0);
                    dst[base +  72] = f2bf(v1);
                    dst[base + 144] = f2bf(v2);
                    dst[base + 216] = f2bf(v3);
                }
            }
        }
        __syncthreads();

        // ---- per head: scores + softmax(exp2) + PV (wave-local M-band) ----
        #pragma unroll
        for (int hh = 0; hh < 2; hh++) {
            const int h = h0 + hh;
            bf16x8 aq = *(const bf16x8*)&Qs[arow * 72 + hh * 32 + kg];
            f32x4 s4[4];
            #pragma unroll
            for (int nt = 0; nt < 4; nt++) {
                bf16x8 bk = *(const bf16x8*)&Ks[(nt * 16 + lrow) * 72 + hh * 32 + kg];
                f32x4 a = (f32x4){0.f, 0.f, 0.f, 0.f};
                a = __builtin_amdgcn_mfma_f32_16x16x32_bf16(aq, bk, a, 0, 0, 0);
                #pragma unroll
                for (int jj = 0; jj < 4; jj++)
                    s4[nt][jj] = a[jj] + rpbl[rpi16[jj][nt] + h] + madd[jj][nt];
            }

            #pragma unroll
            for (int jj = 0; jj < 4; jj++) {
                float m = fmaxf(fmaxf(s4[0][jj], s4[1][jj]), fmaxf(s4[2][jj], s4[3][jj]));
                #pragma unroll
                for (int msk = 1; msk < 16; msk <<= 1) m = fmaxf(m, __shfl_xor(m, msk));
                float e0 = __builtin_amdgcn_exp2f(s4[0][jj] - m);
                float e1 = __builtin_amdgcn_exp2f(s4[1][jj] - m);
                float e2 = __builtin_amdgcn_exp2f(s4[2][jj] - m);
                float e3 = __builtin_amdgcn_exp2f(s4[3][jj] - m);
                float r = e0 + e1 + e2 + e3;
                #pragma unroll
                for (int msk = 1; msk < 16; msk <<= 1) r += __shfl_xor(r, msk);
                float inv = 1.0f / r;
                int prow = (m0 + rg * 4 + jj) * 72;
                Ps[prow +  0 + lrow] = f2bf(e0 * inv);
                Ps[prow + 16 + lrow] = f2bf(e1 * inv);
                Ps[prow + 32 + lrow] = f2bf(e2 * inv);
                Ps[prow + 48 + lrow] = f2bf(e3 * inv);
            }

            #pragma unroll
            for (int nt = 0; nt < 2; nt++) {
                f32x4 a = (f32x4){0.f, 0.f, 0.f, 0.f};
                #pragma unroll
                for (int ks = 0; ks < 2; ks++) {
                    bf16x8 pa = *(const bf16x8*)&Ps[arow * 72 + ks * 32 + kg];
                    bf16x8 bv = *(const bf16x8*)&Vs[(hh * 32 + nt * 16 + lrow) * 72 + ks * 32 + kg];
                    a = __builtin_amdgcn_mfma_f32_16x16x32_bf16(pa, bv, a, 0, 0, 0);
                }
                int hcol = hh * 32 + nt * 16 + lrow;
                int hbase = (m0 + rg * 4) * 72 + hcol;
                Ho[hbase +   0] = f2bf(a[0]);
                Ho[hbase +  72] = f2bf(a[1]);
                Ho[hbase + 144] = f2bf(a[2]);
                Ho[hbase + 216] = f2bf(a[3]);
            }
        }
        __syncthreads();

        // ---- proj, N-split: global B loads hoisted ahead of LDS reads ----
        bf16x8 pj[3][2];
        #pragma unroll
        for (int nt = 0; nt < 3; nt++) {
            const ushort* bp = PjT + (size_t)(wid * 48 + nt * 16 + lrow) * 192 + p * 64 + kg;
            pj[nt][0] = *(const bf16x8*)(bp);
            pj[nt][1] = *(const bf16x8*)(bp + 32);
        }
        bf16x8 aH[4][2];
        #pragma unroll
        for (int m = 0; m < 4; m++)
            #pragma unroll
            for (int ks = 0; ks < 2; ks++)
                aH[m][ks] = *(const bf16x8*)&Ho[(m * 16 + lrow) * 72 + ks * 32 + kg];
        #pragma unroll
        for (int nt = 0; nt < 3; nt++)
            #pragma unroll
            for (int m = 0; m < 4; m++) {
                acc2[nt][m] = __builtin_amdgcn_mfma_f32_16x16x32_bf16(aH[m][0], pj[nt][0], acc2[nt][m], 0, 0, 0);
                acc2[nt][m] = __builtin_amdgcn_mfma_f32_16x16x32_bf16(aH[m][1], pj[nt][1], acc2[nt][m], 0, 0, 0);
            }
    }

    // ---- epilogue: x2 = bf16(x + proj_out + proj_b) (N-split cols, 49 rows) ----
    float pb[3];
    #pragma unroll
    for (int nt = 0; nt < 3; nt++) pb[nt] = proj_b[wid * 48 + nt * 16 + lrow];
    #pragma unroll
    for (int m = 0; m < 4; m++) {
        #pragma unroll
        for (int jj = 0; jj < 4; jj++) {
            int n = m * 16 + rg * 4 + jj;
            if (n < NTOK) {
                int i = (n * 9363) >> 16, j = n - i * 7;
                int hs = wh * 7 + i + SSZ; if (hs >= HW) hs -= HW;
                int ws = ww * 7 + j + SSZ; if (ws >= HW) ws -= HW;
                size_t gb = (((size_t)b * HW + hs) * HW + ws) * CDIM;
                #pragma unroll
                for (int nt = 0; nt < 3; nt++) {
                    int c = wid * 48 + nt * 16 + lrow;
                    x2[gb + c] = f2bf(x[gb + c] + pb[nt] + acc2[nt][m][jj]);
                }
            }
        }
    }
}

// ---------------------------------------------------------------------------
// MFMA MLP v5: x2 input is bf16 (half the staging/residual traffic).
// Chunk 384, N-split waves, in-kernel LN2, 2-deep B prefetch. 75.8 KB LDS.
// ---------------------------------------------------------------------------
__global__ __launch_bounds__(256, 2) void mlp_mfma_kernel(
    const ushort* __restrict__ x2,
    const float*  __restrict__ g2, const float* __restrict__ b2,
    const ushort* __restrict__ W1T, const float* __restrict__ fc1_b,
    const ushort* __restrict__ W2T, const float* __restrict__ fc2_b,
    float* __restrict__ out)
{
    __shared__ ushort A[64 * 200];    // 25600 B
    __shared__ ushort Hs[64 * 392];   // 50176 B -> 75776 B total

    const int tid = threadIdx.x;
    const int l   = tid & 63;
    const int wid = tid >> 6;
    const size_t tok0 = (size_t)blockIdx.x * 64;

    // ---- stage LN2(x2) tile as bf16, stats in-kernel (bf16 input) ----
    {
        int n  = tid >> 2;
        int c0 = (tid & 3) * 48;
        size_t tok = tok0 + n;
        const bf16x8* xr = (const bf16x8*)(x2 + tok * CDIM + c0);
        float f[48];
        float s = 0.0f, q = 0.0f;
        #pragma unroll
        for (int j8 = 0; j8 < 6; j8++) {
            bf16x8 v = xr[j8];
            #pragma unroll
            for (int e = 0; e < 8; e++) {
                float fv = bf2f((ushort)v[e]);
                f[j8 * 8 + e] = fv;
                s += fv;
                q += fv * fv;
            }
        }
        s += __shfl_xor(s, 1); s += __shfl_xor(s, 2);
        q += __shfl_xor(q, 1); q += __shfl_xor(q, 2);
        float mean = s * (1.0f / 192.0f);
        float rstd = rsqrtf(q * (1.0f / 192.0f) - mean * mean + 1e-5f);
        const float4* gg = (const float4*)(g2 + c0);
        const float4* bb = (const float4*)(b2 + c0);
        #pragma unroll
        for (int j4 = 0; j4 < 12; j4++) {
            float4 g = gg[j4], b = bb[j4];
            int c = n * 200 + c0 + j4 * 4;
            unsigned p0 = pk2bf((f[j4 * 4 + 0] - mean) * rstd * g.x + b.x,
                                (f[j4 * 4 + 1] - mean) * rstd * g.y + b.y);
            unsigned p1 = pk2bf((f[j4 * 4 + 2] - mean) * rstd * g.z + b.z,
                                (f[j4 * 4 + 3] - mean) * rstd * g.w + b.w);
            *(uint2*)&A[c] = make_uint2(p0, p1);
        }
    }
    __syncthreads();

    const int lrow = l & 15;
    const int rg   = l >> 4;
    const int kg   = rg * 8;

    f32x4 acc2[3][4];
    #pragma unroll
    for (int nt = 0; nt < 3; nt++)
        #pragma unroll
        for (int m = 0; m < 4; m++) acc2[nt][m] = (f32x4){0.f, 0.f, 0.f, 0.f};

    for (int ch = 0; ch < 2; ch++) {
        const int h0 = ch * 384;
        if (ch) __syncthreads();   // prior GEMM2 reads of Hs complete

        // hoisted fc1 biases for this wave's 6 tiles
        float bias1[6];
        #pragma unroll
        for (int nt = 0; nt < 6; nt++)
            bias1[nt] = fc1_b[h0 + wid * 96 + nt * 16 + lrow];

        // first B tile prefetch (issue before LDS a1 reads)
        bf16x8 wb0[6], wb1[6];
        {
            const ushort* bp = W1T + (size_t)(h0 + wid * 96 + lrow) * 192 + kg;
            #pragma unroll
            for (int ks = 0; ks < 6; ks++) wb0[ks] = *(const bf16x8*)(bp + ks * 32);
        }

        bf16x8 a1[4][6];
        #pragma unroll
        for (int m = 0; m < 4; m++)
            #pragma unroll
            for (int ks = 0; ks < 6; ks++)
                a1[m][ks] = *(const bf16x8*)&A[(m * 16 + lrow) * 200 + ks * 32 + kg];

        // ---- GEMM1 with 2-deep pipeline: H[:, wave 96-col slice] ----
        #pragma unroll
        for (int nt = 0; nt < 6; nt++) {
            if (nt < 5) {
                const ushort* bp = W1T + (size_t)(h0 + wid * 96 + (nt + 1) * 16 + lrow) * 192 + kg;
                bf16x8* nxt = (nt & 1) ? wb0 : wb1;
                #pragma unroll
                for (int ks = 0; ks < 6; ks++) nxt[ks] = *(const bf16x8*)(bp + ks * 32);
            }
            const bf16x8* cur = (nt & 1) ? wb1 : wb0;
            const int ncol = wid * 96 + nt * 16;
            #pragma unroll
            for (int m = 0; m < 4; m++) {
                f32x4 a = (f32x4){0.f, 0.f, 0.f, 0.f};
                #pragma unroll
                for (int ks = 0; ks < 6; ks++)
                    a = __builtin_amdgcn_mfma_f32_16x16x32_bf16(a1[m][ks], cur[ks], a, 0, 0, 0);
                #pragma unroll
                for (int jj = 0; jj < 4; jj++)
                    Hs[(m * 16 + rg * 4 + jj) * 392 + ncol + lrow] = f2bf(gelu_f(a[jj] + bias1[nt]));
            }
        }
        __syncthreads();

        // ---- GEMM2 with 2-deep pipeline: acc2 += H_chunk @ W2 slice ----
        bf16x8 c0[12], c1[12];
        {
            #pragma unroll
            for (int nt = 0; nt < 3; nt++) {
                const ushort* bp = W2T + (size_t)(wid * 48 + nt * 16 + lrow) * 768 + h0 + kg;
                #pragma unroll
                for (int ks = 0; ks < 4; ks++) c0[nt * 4 + ks] = *(const bf16x8*)(bp + ks * 32);
            }
        }
        #pragma unroll
        for (int ksb = 0; ksb < 3; ksb++) {
            const int kb = ksb * 128;
            if (ksb < 2) {
                bf16x8* nxt = (ksb & 1) ? c0 : c1;
                #pragma unroll
                for (int nt = 0; nt < 3; nt++) {
                    const ushort* bp = W2T + (size_t)(wid * 48 + nt * 16 + lrow) * 768 + h0 + kb + 128 + kg;
                    #pragma unroll
                    for (int ks = 0; ks < 4; ks++) nxt[nt * 4 + ks] = *(const bf16x8*)(bp + ks * 32);
                }
            }
            const bf16x8* cur = (ksb & 1) ? c1 : c0;
            bf16x8 aH[4][4];
            #pragma unroll
            for (int m = 0; m < 4; m++)
                #pragma unroll
                for (int ks = 0; ks < 4; ks++)
                    aH[m][ks] = *(const bf16x8*)&Hs[(m * 16 + lrow) * 392 + kb + ks * 32 + kg];
            #pragma unroll
            for (int nt = 0; nt < 3; nt++)
                #pragma unroll
                for (int m = 0; m < 4; m++)
                    #pragma unroll
                    for (int ks = 0; ks < 4; ks++)
                        acc2[nt][m] = __builtin_amdgcn_mfma_f32_16x16x32_bf16(
                            aH[m][ks], cur[nt * 4 + ks], acc2[nt][m], 0, 0, 0);
        }
    }

    // ---- epilogue: out = x2 + acc2 + fc2_b (bf16 residual read) ----
    #pragma unroll
    for (int nt = 0; nt < 3; nt++) {
        int c = wid * 48 + nt * 16 + lrow;
        float fb = fc2_b[c];
        #pragma unroll
        for (int m = 0; m < 4; m++) {
            #pragma unroll
            for (int jj = 0; jj < 4; jj++) {
                size_t tok = tok0 + m * 16 + rg * 4 + jj;
                out[tok * CDIM + c] = bf2f(x2[tok * CDIM + c]) + acc2[nt][m][jj] + fb;
            }
        }
    }
}

// ---------------------------------------------------------------------------
extern "C" void kernel_launch(void* const* d_in, const int* in_sizes, int n_in,
                              void* d_out, int out_size, void* d_ws, size_t ws_size,
                              hipStream_t stream) {
    const float* x      = (const float*)d_in[0];
    const float* g1     = (const float*)d_in[1];
    const float* b1     = (const float*)d_in[2];
    const float* qkv_w  = (const float*)d_in[3];
    const float* qkv_b  = (const float*)d_in[4];
    const float* rpb    = (const float*)d_in[5];
    const float* proj_w = (const float*)d_in[6];
    const float* proj_b = (const float*)d_in[7];
    const float* g2     = (const float*)d_in[8];
    const float* b2     = (const float*)d_in[9];
    const float* fc1_w  = (const float*)d_in[10];
    const float* fc1_b  = (const float*)d_in[11];
    const float* fc2_w  = (const float*)d_in[12];
    const float* fc2_b  = (const float*)d_in[13];
    float* out = (float*)d_out;

    char* ws = (char*)d_ws;
    ushort* x2     = (ushort*)ws;                     // 38535168 B (bf16)
    ushort* W1T    = (ushort*)(ws + 38535168);        //   294912 B
    ushort* W2T    = (ushort*)(ws + 38830080);        //   294912 B
    ushort* WqkvT  = (ushort*)(ws + 39124992);        //   221184 B
    ushort* PjT    = (ushort*)(ws + 39346176);        //    73728 B

    prep_weights_kernel<<<576, 256, 0, stream>>>(fc1_w, fc2_w, qkv_w, proj_w,
                                                 W1T, W2T, WqkvT, PjT);
    attn_mfma_kernel<<<32 * 64, 256, 0, stream>>>(x, g1, b1,
                                                  WqkvT, qkv_b, rpb,
                                                  PjT, proj_b, x2);
    mlp_mfma_kernel<<<TTOK / 64, 256, 0, stream>>>(x2, g2, b2,
                                                   W1T, fc1_b, W2T, fc2_b, out);
}

// Round 18
// 275.531 us; speedup vs baseline: 2.1882x; 1.0255x over previous
//
#include <hip/hip_runtime.h>
#include <hip/hip_bf16.h>

#define CDIM 192
#define WSZ 7
#define SSZ 3
#define NHEAD 6
#define HD 32
#define NTOK 49          // tokens per window
#define HW 56
#define TTOK (32*56*56)  // 100352 tokens total

#define QSCALE_LOG2E 0.25507817580918256f   // (1/sqrt(32)) * log2(e)
#define MASK_LOG2E  -144.26950408889634f    // -100 * log2(e)
#define LOG2E        1.4426950408889634f

typedef __attribute__((ext_vector_type(8))) short bf16x8;
typedef __attribute__((ext_vector_type(4))) float f32x4;

// manual RNE f32->bf16 (known good)
__device__ inline ushort f2bf(float v) {
    union { float f; unsigned u; } x; x.f = v;
    unsigned r = x.u + 0x7fff + ((x.u >> 16) & 1);
    return (ushort)(r >> 16);
}
// two f32 -> one packed dword (manual, no asm)
__device__ inline unsigned pk2bf(float lo, float hi) {
    return (unsigned)f2bf(lo) | ((unsigned)f2bf(hi) << 16);
}
// bf16 bits -> f32 (exact)
__device__ inline float bf2f(ushort u) {
    union { unsigned u; float f; } x; x.u = ((unsigned)u) << 16;
    return x.f;
}

__device__ inline float gelu_f(float x) {
    // x * sigmoid(2c1*x*(1+c2*x^2)) == tanh-form GELU, exp2 folded
    float x2 = x * x;
    float t  = x * fmaf(x2, 0.10287358f, 2.3022157f);   // (2c1, 2c1c2) * log2(e)
    float e  = __builtin_amdgcn_exp2f(-t);
    return x * __builtin_amdgcn_rcpf(1.0f + e);
}

// ---------------------------------------------------------------------------
// Weight prep: bf16 N-major transposes. Q-part of WqkvT pre-scaled by
// (1/sqrt(hd))*log2(e) so softmax runs in the exp2 domain.
// ---------------------------------------------------------------------------
__global__ __launch_bounds__(256) void prep_weights_kernel(
    const float* __restrict__ fc1_w, const float* __restrict__ fc2_w,
    const float* __restrict__ qkv_w, const float* __restrict__ proj_w,
    ushort* __restrict__ W1T, ushort* __restrict__ W2T,
    ushort* __restrict__ WqkvT, ushort* __restrict__ PjT) {
    int idx = blockIdx.x * 256 + threadIdx.x;  // grid covers exactly 147456
    {
        int n = idx / 192, k = idx - n * 192;
        W1T[idx] = f2bf(fc1_w[k * 768 + n]);
    }
    {
        int c = idx / 768, k = idx - c * 768;
        W2T[idx] = f2bf(fc2_w[k * 192 + c]);
    }
    if (idx < 576 * 192) {
        int n = idx / 192, k = idx - n * 192;
        float v = qkv_w[k * 576 + n];
        if (n < 192) v *= QSCALE_LOG2E;
        WqkvT[idx] = f2bf(v);
    }
    if (idx < 192 * 192) {
        int n = idx / 192, k = idx - n * 192;
        PjT[idx] = f2bf(proj_w[k * 192 + n]);
    }
}

// ---------------------------------------------------------------------------
// MFMA shifted-window attention: head-pair loop, N-split QKV (serial B loads)
// / proj, M-split scores/softmax(exp2)/PV. In-kernel LN1, LDS A staging.
// Softmax: no max-sub (scores bounded, exp2 domain), norm deferred to PV out.
// x2 written as bf16. LDS 75.7 KB -> 2 blk/CU.
// ---------------------------------------------------------------------------
__global__ __launch_bounds__(256, 2) void attn_mfma_kernel(
    const float*  __restrict__ x,
    const float*  __restrict__ g1, const float* __restrict__ b1,
    const ushort* __restrict__ WqkvT, const float* __restrict__ qkv_b,
    const float*  __restrict__ rpb,
    const ushort* __restrict__ PjT, const float* __restrict__ proj_b,
    ushort* __restrict__ x2)
{
    __shared__ ushort A[64 * 200];    // 25600 B  LN'd tokens (rows 49-63 zero)
    __shared__ ushort Qs[64 * 72];    //  9216 B  q (pre-scaled), [tok][pairdim]
    __shared__ ushort Ks[64 * 72];    //  9216 B  k, [tok][pairdim]
    __shared__ ushort Vs[64 * 72];    //  9216 B  v, [pairdim][tok]
    __shared__ ushort Ps[64 * 72];    //  9216 B  P (unnormalized), wave-private rows
    __shared__ ushort Ho[64 * 72];    //  9216 B  head-pair out, [tok][pairdim]
    __shared__ float  rpbl[169 * 6];  //  4056 B   -> 75736 B total

    const int bid = blockIdx.x;
    const int b   = bid >> 6;
    const int w   = bid & 63;
    const int wh  = w >> 3, ww = w & 7;
    const int tid = threadIdx.x;
    const int l   = tid & 63;
    const int wid = tid >> 6;

    for (int e = tid; e < 169 * 6; e += 256) rpbl[e] = rpb[e] * LOG2E;

    // ---- stage A = LN1(x window, shifted) with in-kernel stats ----
    {
        int n  = tid >> 2;
        int c0 = (tid & 3) * 48;
        if (n < NTOK) {
            int i = n / 7, j = n - i * 7;
            int hs = wh * 7 + i + SSZ; if (hs >= HW) hs -= HW;
            int ws = ww * 7 + j + SSZ; if (ws >= HW) ws -= HW;
            size_t tok = ((size_t)b * HW + hs) * HW + ws;
            const float4* xr = (const float4*)(x + tok * CDIM + c0);
            float4 f[12];
            float s = 0.0f, q = 0.0f;
            #pragma unroll
            for (int j4 = 0; j4 < 12; j4++) {
                float4 v = xr[j4]; f[j4] = v;
                s += v.x + v.y + v.z + v.w;
                q += v.x * v.x + v.y * v.y + v.z * v.z + v.w * v.w;
            }
            s += __shfl_xor(s, 1); s += __shfl_xor(s, 2);
            q += __shfl_xor(q, 1); q += __shfl_xor(q, 2);
            float mean = s * (1.0f / 192.0f);
            float rstd = rsqrtf(q * (1.0f / 192.0f) - mean * mean + 1e-5f);
            const float4* gg = (const float4*)(g1 + c0);
            const float4* bb = (const float4*)(b1 + c0);
            #pragma unroll
            for (int j4 = 0; j4 < 12; j4++) {
                float4 v = f[j4], g = gg[j4], bv = bb[j4];
                int c = n * 200 + c0 + j4 * 4;
                unsigned p0 = pk2bf((v.x - mean) * rstd * g.x + bv.x,
                                    (v.y - mean) * rstd * g.y + bv.y);
                unsigned p1 = pk2bf((v.z - mean) * rstd * g.z + bv.z,
                                    (v.w - mean) * rstd * g.w + bv.w);
                *(uint2*)&A[c] = make_uint2(p0, p1);
            }
        } else {
            #pragma unroll
            for (int j4 = 0; j4 < 12; j4++) {
                int c = n * 200 + c0 + j4 * 4;
                *(uint2*)&A[c] = make_uint2(0u, 0u);
            }
        }
    }
    __syncthreads();

    const int lrow = l & 15;
    const int rg   = l >> 4;
    const int kg   = rg * 8;
    const int m0   = wid * 16;
    const int arow = m0 + lrow;

    // per-lane bias/mask tables: score[i=m0+rg*4+jj][j=nt*16+lrow]
    int   rpi16[4][4];
    float madd[4][4];
    #pragma unroll
    for (int jj = 0; jj < 4; jj++) {
        int i  = m0 + rg * 4 + jj;
        int ih = (i * 9363) >> 16, iw = i - ih * 7;
        int pi = wh * 7 + ih, qi = ww * 7 + iw;
        int ci = (pi < 49 ? 0 : (pi < 53 ? 1 : 2)) * 3 + (qi < 49 ? 0 : (qi < 53 ? 1 : 2));
        #pragma unroll
        for (int nt = 0; nt < 4; nt++) {
            int j  = nt * 16 + lrow;
            int jh = (j * 9363) >> 16, jw = j - jh * 7;
            int pj = wh * 7 + jh, qj = ww * 7 + jw;
            int cj = (pj < 49 ? 0 : (pj < 53 ? 1 : 2)) * 3 + (qj < 49 ? 0 : (qj < 53 ? 1 : 2));
            int rpi = (ih - jh + 6) * 13 + (iw - jw + 6);
            rpi = rpi < 0 ? 0 : (rpi > 168 ? 168 : rpi);
            rpi16[jj][nt] = rpi * 6;
            madd[jj][nt] = (j >= NTOK) ? MASK_LOG2E * 8.0f : ((ci != cj) ? MASK_LOG2E : 0.0f);
        }
    }

    f32x4 acc2[3][4];   // proj: [n-tile][m-tile], wave owns cols wid*48..+48
    #pragma unroll
    for (int nt = 0; nt < 3; nt++)
        #pragma unroll
        for (int m = 0; m < 4; m++) acc2[nt][m] = (f32x4){0.f, 0.f, 0.f, 0.f};

    for (int p = 0; p < 3; p++) {
        const int h0 = p * 2;

        bf16x8 a1[4][6];
        #pragma unroll
        for (int m = 0; m < 4; m++)
            #pragma unroll
            for (int ks = 0; ks < 6; ks++)
                a1[m][ks] = *(const bf16x8*)&A[(m * 16 + lrow) * 200 + ks * 32 + kg];

        // ---- QKV, N-split: wave handles 3 of 12 tiles, serial B loads ----
        #pragma unroll
        for (int tt = 0; tt < 3; tt++) {
            const int t    = wid * 3 + tt;
            const int kind = t >> 2;          // 0=Q 1=K 2=V (wave-uniform)
            const int sub  = t & 3;
            const int hh   = sub >> 1, half = sub & 1;
            const int dim2 = hh * 32 + half * 16 + lrow;
            const int nglob = kind * 192 + (h0 + hh) * 32 + half * 16;
            const ushort* bp = WqkvT + (size_t)(nglob + lrow) * 192 + kg;
            bf16x8 bfr[6];
            #pragma unroll
            for (int ks = 0; ks < 6; ks++)
                bfr[ks] = *(const bf16x8*)(bp + ks * 32);
            float bias = qkv_b[nglob + lrow];
            if (kind == 0) bias *= QSCALE_LOG2E;   // W already pre-scaled
            #pragma unroll
            for (int m = 0; m < 4; m++) {
                f32x4 a = (f32x4){0.f, 0.f, 0.f, 0.f};
                #pragma unroll
                for (int ks = 0; ks < 6; ks++)
                    a = __builtin_amdgcn_mfma_f32_16x16x32_bf16(a1[m][ks], bfr[ks], a, 0, 0, 0);
                float v0 = a[0] + bias, v1 = a[1] + bias;
                float v2 = a[2] + bias, v3 = a[3] + bias;
                if (kind == 2) {
                    // 4 consecutive tokens in one row: packed 8B store
                    *(uint2*)&Vs[dim2 * 72 + m * 16 + rg * 4] =
                        make_uint2(pk2bf(v0, v1), pk2bf(v2, v3));
                } else {
                    ushort* dst = (kind == 0) ? Qs : Ks;
                    int base = (m * 16 + rg * 4) * 72 + dim2;
                    dst[base +   0] = f2bf(v0);
                    dst[base +  72] = f2bf(v1);
                    dst[base + 144] = f2bf(v2);
                    dst[base + 216] = f2bf(v3);
                }
            }
        }
        __syncthreads();

        // ---- per head: scores + softmax(exp2, no max-sub) + PV ----
        #pragma unroll
        for (int hh = 0; hh < 2; hh++) {
            const int h = h0 + hh;
            bf16x8 aq = *(const bf16x8*)&Qs[arow * 72 + hh * 32 + kg];
            f32x4 s4[4];
            #pragma unroll
            for (int nt = 0; nt < 4; nt++) {
                bf16x8 bk = *(const bf16x8*)&Ks[(nt * 16 + lrow) * 72 + hh * 32 + kg];
                f32x4 a = (f32x4){0.f, 0.f, 0.f, 0.f};
                a = __builtin_amdgcn_mfma_f32_16x16x32_bf16(aq, bk, a, 0, 0, 0);
                #pragma unroll
                for (int jj = 0; jj < 4; jj++)
                    s4[nt][jj] = a[jj] + rpbl[rpi16[jj][nt] + h] + madd[jj][nt];
            }

            // scores are tiny (sigma ~0.1 in log2 domain): exp2 directly,
            // defer the 1/sum normalization to the PV output.
            float inv[4];
            #pragma unroll
            for (int jj = 0; jj < 4; jj++) {
                float e0 = __builtin_amdgcn_exp2f(s4[0][jj]);
                float e1 = __builtin_amdgcn_exp2f(s4[1][jj]);
                float e2 = __builtin_amdgcn_exp2f(s4[2][jj]);
                float e3 = __builtin_amdgcn_exp2f(s4[3][jj]);
                float r = e0 + e1 + e2 + e3;
                #pragma unroll
                for (int msk = 1; msk < 16; msk <<= 1) r += __shfl_xor(r, msk);
                inv[jj] = __builtin_amdgcn_rcpf(r);
                int prow = (m0 + rg * 4 + jj) * 72;
                Ps[prow +  0 + lrow] = f2bf(e0);
                Ps[prow + 16 + lrow] = f2bf(e1);
                Ps[prow + 32 + lrow] = f2bf(e2);
                Ps[prow + 48 + lrow] = f2bf(e3);
            }

            #pragma unroll
            for (int nt = 0; nt < 2; nt++) {
                f32x4 a = (f32x4){0.f, 0.f, 0.f, 0.f};
                #pragma unroll
                for (int ks = 0; ks < 2; ks++) {
                    bf16x8 pa = *(const bf16x8*)&Ps[arow * 72 + ks * 32 + kg];
                    bf16x8 bv = *(const bf16x8*)&Vs[(hh * 32 + nt * 16 + lrow) * 72 + ks * 32 + kg];
                    a = __builtin_amdgcn_mfma_f32_16x16x32_bf16(pa, bv, a, 0, 0, 0);
                }
                int hcol = hh * 32 + nt * 16 + lrow;
                int hbase = (m0 + rg * 4) * 72 + hcol;
                Ho[hbase +   0] = f2bf(a[0] * inv[0]);
                Ho[hbase +  72] = f2bf(a[1] * inv[1]);
                Ho[hbase + 144] = f2bf(a[2] * inv[2]);
                Ho[hbase + 216] = f2bf(a[3] * inv[3]);
            }
        }
        __syncthreads();

        // ---- proj, N-split: global B loads hoisted ahead of LDS reads ----
        bf16x8 pj[3][2];
        #pragma unroll
        for (int nt = 0; nt < 3; nt++) {
            const ushort* bp = PjT + (size_t)(wid * 48 + nt * 16 + lrow) * 192 + p * 64 + kg;
            pj[nt][0] = *(const bf16x8*)(bp);
            pj[nt][1] = *(const bf16x8*)(bp + 32);
        }
        bf16x8 aH[4][2];
        #pragma unroll
        for (int m = 0; m < 4; m++)
            #pragma unroll
            for (int ks = 0; ks < 2; ks++)
                aH[m][ks] = *(const bf16x8*)&Ho[(m * 16 + lrow) * 72 + ks * 32 + kg];
        #pragma unroll
        for (int nt = 0; nt < 3; nt++)
            #pragma unroll
            for (int m = 0; m < 4; m++) {
                acc2[nt][m] = __builtin_amdgcn_mfma_f32_16x16x32_bf16(aH[m][0], pj[nt][0], acc2[nt][m], 0, 0, 0);
                acc2[nt][m] = __builtin_amdgcn_mfma_f32_16x16x32_bf16(aH[m][1], pj[nt][1], acc2[nt][m], 0, 0, 0);
            }
    }

    // ---- epilogue: x2 = bf16(x + proj_out + proj_b) (N-split cols, 49 rows) ----
    float pb[3];
    #pragma unroll
    for (int nt = 0; nt < 3; nt++) pb[nt] = proj_b[wid * 48 + nt * 16 + lrow];
    #pragma unroll
    for (int m = 0; m < 4; m++) {
        #pragma unroll
        for (int jj = 0; jj < 4; jj++) {
            int n = m * 16 + rg * 4 + jj;
            if (n < NTOK) {
                int i = (n * 9363) >> 16, j = n - i * 7;
                int hs = wh * 7 + i + SSZ; if (hs >= HW) hs -= HW;
                int ws = ww * 7 + j + SSZ; if (ws >= HW) ws -= HW;
                size_t gb = (((size_t)b * HW + hs) * HW + ws) * CDIM;
                #pragma unroll
                for (int nt = 0; nt < 3; nt++) {
                    int c = wid * 48 + nt * 16 + lrow;
                    x2[gb + c] = f2bf(x[gb + c] + pb[nt] + acc2[nt][m][jj]);
                }
            }
        }
    }
}

// ---------------------------------------------------------------------------
// MFMA MLP v5: x2 input is bf16 (half the staging/residual traffic).
// Chunk 384, N-split waves, in-kernel LN2, 2-deep B prefetch. 75.8 KB LDS.
// ---------------------------------------------------------------------------
__global__ __launch_bounds__(256, 2) void mlp_mfma_kernel(
    const ushort* __restrict__ x2,
    const float*  __restrict__ g2, const float* __restrict__ b2,
    const ushort* __restrict__ W1T, const float* __restrict__ fc1_b,
    const ushort* __restrict__ W2T, const float* __restrict__ fc2_b,
    float* __restrict__ out)
{
    __shared__ ushort A[64 * 200];    // 25600 B
    __shared__ ushort Hs[64 * 392];   // 50176 B -> 75776 B total

    const int tid = threadIdx.x;
    const int l   = tid & 63;
    const int wid = tid >> 6;
    const size_t tok0 = (size_t)blockIdx.x * 64;

    // ---- stage LN2(x2) tile as bf16, stats in-kernel (bf16 input) ----
    {
        int n  = tid >> 2;
        int c0 = (tid & 3) * 48;
        size_t tok = tok0 + n;
        const bf16x8* xr = (const bf16x8*)(x2 + tok * CDIM + c0);
        float f[48];
        float s = 0.0f, q = 0.0f;
        #pragma unroll
        for (int j8 = 0; j8 < 6; j8++) {
            bf16x8 v = xr[j8];
            #pragma unroll
            for (int e = 0; e < 8; e++) {
                float fv = bf2f((ushort)v[e]);
                f[j8 * 8 + e] = fv;
                s += fv;
                q += fv * fv;
            }
        }
        s += __shfl_xor(s, 1); s += __shfl_xor(s, 2);
        q += __shfl_xor(q, 1); q += __shfl_xor(q, 2);
        float mean = s * (1.0f / 192.0f);
        float rstd = rsqrtf(q * (1.0f / 192.0f) - mean * mean + 1e-5f);
        const float4* gg = (const float4*)(g2 + c0);
        const float4* bb = (const float4*)(b2 + c0);
        #pragma unroll
        for (int j4 = 0; j4 < 12; j4++) {
            float4 g = gg[j4], b = bb[j4];
            int c = n * 200 + c0 + j4 * 4;
            unsigned p0 = pk2bf((f[j4 * 4 + 0] - mean) * rstd * g.x + b.x,
                                (f[j4 * 4 + 1] - mean) * rstd * g.y + b.y);
            unsigned p1 = pk2bf((f[j4 * 4 + 2] - mean) * rstd * g.z + b.z,
                                (f[j4 * 4 + 3] - mean) * rstd * g.w + b.w);
            *(uint2*)&A[c] = make_uint2(p0, p1);
        }
    }
    __syncthreads();

    const int lrow = l & 15;
    const int rg   = l >> 4;
    const int kg   = rg * 8;

    f32x4 acc2[3][4];
    #pragma unroll
    for (int nt = 0; nt < 3; nt++)
        #pragma unroll
        for (int m = 0; m < 4; m++) acc2[nt][m] = (f32x4){0.f, 0.f, 0.f, 0.f};

    for (int ch = 0; ch < 2; ch++) {
        const int h0 = ch * 384;
        if (ch) __syncthreads();   // prior GEMM2 reads of Hs complete

        // hoisted fc1 biases for this wave's 6 tiles
        float bias1[6];
        #pragma unroll
        for (int nt = 0; nt < 6; nt++)
            bias1[nt] = fc1_b[h0 + wid * 96 + nt * 16 + lrow];

        // first B tile prefetch (issue before LDS a1 reads)
        bf16x8 wb0[6], wb1[6];
        {
            const ushort* bp = W1T + (size_t)(h0 + wid * 96 + lrow) * 192 + kg;
            #pragma unroll
            for (int ks = 0; ks < 6; ks++) wb0[ks] = *(const bf16x8*)(bp + ks * 32);
        }

        bf16x8 a1[4][6];
        #pragma unroll
        for (int m = 0; m < 4; m++)
            #pragma unroll
            for (int ks = 0; ks < 6; ks++)
                a1[m][ks] = *(const bf16x8*)&A[(m * 16 + lrow) * 200 + ks * 32 + kg];

        // ---- GEMM1 with 2-deep pipeline: H[:, wave 96-col slice] ----
        #pragma unroll
        for (int nt = 0; nt < 6; nt++) {
            if (nt < 5) {
                const ushort* bp = W1T + (size_t)(h0 + wid * 96 + (nt + 1) * 16 + lrow) * 192 + kg;
                bf16x8* nxt = (nt & 1) ? wb0 : wb1;
                #pragma unroll
                for (int ks = 0; ks < 6; ks++) nxt[ks] = *(const bf16x8*)(bp + ks * 32);
            }
            const bf16x8* cur = (nt & 1) ? wb1 : wb0;
            const int ncol = wid * 96 + nt * 16;
            #pragma unroll
            for (int m = 0; m < 4; m++) {
                f32x4 a = (f32x4){0.f, 0.f, 0.f, 0.f};
                #pragma unroll
                for (int ks = 0; ks < 6; ks++)
                    a = __builtin_amdgcn_mfma_f32_16x16x32_bf16(a1[m][ks], cur[ks], a, 0, 0, 0);
                #pragma unroll
                for (int jj = 0; jj < 4; jj++)
                    Hs[(m * 16 + rg * 4 + jj) * 392 + ncol + lrow] = f2bf(gelu_f(a[jj] + bias1[nt]));
            }
        }
        __syncthreads();

        // ---- GEMM2 with 2-deep pipeline: acc2 += H_chunk @ W2 slice ----
        bf16x8 c0[12], c1[12];
        {
            #pragma unroll
            for (int nt = 0; nt < 3; nt++) {
                const ushort* bp = W2T + (size_t)(wid * 48 + nt * 16 + lrow) * 768 + h0 + kg;
                #pragma unroll
                for (int ks = 0; ks < 4; ks++) c0[nt * 4 + ks] = *(const bf16x8*)(bp + ks * 32);
            }
        }
        #pragma unroll
        for (int ksb = 0; ksb < 3; ksb++) {
            const int kb = ksb * 128;
            if (ksb < 2) {
                bf16x8* nxt = (ksb & 1) ? c0 : c1;
                #pragma unroll
                for (int nt = 0; nt < 3; nt++) {
                    const ushort* bp = W2T + (size_t)(wid * 48 + nt * 16 + lrow) * 768 + h0 + kb + 128 + kg;
                    #pragma unroll
                    for (int ks = 0; ks < 4; ks++) nxt[nt * 4 + ks] = *(const bf16x8*)(bp + ks * 32);
                }
            }
            const bf16x8* cur = (ksb & 1) ? c1 : c0;
            bf16x8 aH[4][4];
            #pragma unroll
            for (int m = 0; m < 4; m++)
                #pragma unroll
                for (int ks = 0; ks < 4; ks++)
                    aH[m][ks] = *(const bf16x8*)&Hs[(m * 16 + lrow) * 392 + kb + ks * 32 + kg];
            #pragma unroll
            for (int nt = 0; nt < 3; nt++)
                #pragma unroll
                for (int m = 0; m < 4; m++)
                    #pragma unroll
                    for (int ks = 0; ks < 4; ks++)
                        acc2[nt][m] = __builtin_amdgcn_mfma_f32_16x16x32_bf16(
                            aH[m][ks], cur[nt * 4 + ks], acc2[nt][m], 0, 0, 0);
        }
    }

    // ---- epilogue: out = x2 + acc2 + fc2_b (bf16 residual read) ----
    #pragma unroll
    for (int nt = 0; nt < 3; nt++) {
        int c = wid * 48 + nt * 16 + lrow;
        float fb = fc2_b[c];
        #pragma unroll
        for (int m = 0; m < 4; m++) {
            #pragma unroll
            for (int jj = 0; jj < 4; jj++) {
                size_t tok = tok0 + m * 16 + rg * 4 + jj;
                out[tok * CDIM + c] = bf2f(x2[tok * CDIM + c]) + acc2[nt][m][jj] + fb;
            }
        }
    }
}

// ---------------------------------------------------------------------------
extern "C" void kernel_launch(void* const* d_in, const int* in_sizes, int n_in,
                              void* d_out, int out_size, void* d_ws, size_t ws_size,
                              hipStream_t stream) {
    const float* x      = (const float*)d_in[0];
    const float* g1     = (const float*)d_in[1];
    const float* b1     = (const float*)d_in[2];
    const float* qkv_w  = (const float*)d_in[3];
    const float* qkv_b  = (const float*)d_in[4];
    const float* rpb    = (const float*)d_in[5];
    const float* proj_w = (const float*)d_in[6];
    const float* proj_b = (const float*)d_in[7];
    const float* g2     = (const float*)d_in[8];
    const float* b2     = (const float*)d_in[9];
    const float* fc1_w  = (const float*)d_in[10];
    const float* fc1_b  = (const float*)d_in[11];
    const float* fc2_w  = (const float*)d_in[12];
    const float* fc2_b  = (const float*)d_in[13];
    float* out = (float*)d_out;

    char* ws = (char*)d_ws;
    ushort* x2     = (ushort*)ws;                     // 38535168 B (bf16)
    ushort* W1T    = (ushort*)(ws + 38535168);        //   294912 B
    ushort* W2T    = (ushort*)(ws + 38830080);        //   294912 B
    ushort* WqkvT  = (ushort*)(ws + 39124992);        //   221184 B
    ushort* PjT    = (ushort*)(ws + 39346176);        //    73728 B

    prep_weights_kernel<<<576, 256, 0, stream>>>(fc1_w, fc2_w, qkv_w, proj_w,
                                                 W1T, W2T, WqkvT, PjT);
    attn_mfma_kernel<<<32 * 64, 256, 0, stream>>>(x, g1, b1,
                                                  WqkvT, qkv_b, rpb,
                                                  PjT, proj_b, x2);
    mlp_mfma_kernel<<<TTOK / 64, 256, 0, stream>>>(x2, g2, b2,
                                                   W1T, fc1_b, W2T, fc2_b, out);
}